// Round 18
// baseline (607.009 us; speedup 1.0000x reference)
//
#include <hip/hip_runtime.h>

#define BB 16
#define CC 256
#define NN 4096
#define MM 1024
#define EPSV 1e-5f
#define SCALE (1.0f/16.0f)   // 1/sqrt(C)

// ---- workspace layout (float offsets). ----
#define OFF_MU    0            // 4096  (mu; dead after transpose_score -> u[257], b2, wob)
#define OFF_SCORE 4096         // 65536 (score; dead after select -> beta)
#define OFF_IDX   69632        // 32768 ints (idx_s then idx_g)
#define OFF_U     102400       // 65536 (WoWv f32 scratch)
#define OFF_WF12  233472       // 65536 (Wf12 f32)
#define OFF_BVZ   299008       // 256
#define OFF_BZ    299264       // 256
#define OFF_W16   299520       // 4 bf16 weight mats = 131072 floats
#define OFF_XG    430592       // Xg bf16 [16*1024][256] = 2097152 floats
#define OFF_K16   2527744      // K'' bf16 = 2097152 floats
#define OFF_VT16  4624896      // Vt bf16 = 2097152 floats
#define OFF_Z     6722048      // 16777216 floats
#define OFF_BN    23499264     // 512

typedef __attribute__((ext_vector_type(8))) short s16x8;
typedef __attribute__((ext_vector_type(4))) float f32x4;

__device__ __forceinline__ unsigned short f2bf(float f) {
    unsigned int u = __float_as_uint(f);
    return (unsigned short)((u + 0x7FFFu + ((u >> 16) & 1u)) >> 16);
}
__device__ __forceinline__ float bf2f(unsigned short h) {
    return __uint_as_float(((unsigned int)h) << 16);
}

__global__ __launch_bounds__(256) void zero_bn_kernel(float* bn) {
    int t = threadIdx.x;
    bn[t] = 0.f; bn[t + CC] = 0.f;
}

__global__ __launch_bounds__(256) void zero_rsum_kernel(float* r) {
    r[blockIdx.x * 256 + threadIdx.x] = 0.f;
}

// mu[b,c] = mean over n of x[b,c,n]  (float4 loads, 4 iters/thread)
__global__ __launch_bounds__(256) void mean_kernel(const float* __restrict__ x, float* __restrict__ mu) {
    int c = blockIdx.x, b = blockIdx.y, t = threadIdx.x;
    const float4* p = (const float4*)(x + ((size_t)b * CC + c) * NN);
    float s = 0.f;
    for (int n = t; n < NN / 4; n += 256) { float4 v = p[n]; s += (v.x + v.y) + (v.z + v.w); }
    __shared__ float red[256];
    red[t] = s; __syncthreads();
    for (int w = 128; w > 0; w >>= 1) { if (t < w) red[t] += red[t + w]; __syncthreads(); }
    if (t == 0) mu[b * CC + c] = red[0] * (1.0f / NN);
}

// x [B][C][N] f32 -> xT16 [B][N][C] bf16, fused with score accumulation
__global__ __launch_bounds__(256) void transpose_score_kernel(const float* __restrict__ x,
                                                              const float* __restrict__ mu,
                                                              unsigned short* __restrict__ xT,
                                                              float* __restrict__ score) {
    __shared__ float tile[32][33];
    __shared__ float smu[32];
    int b = blockIdx.z, c0 = blockIdx.y * 32, n0 = blockIdx.x * 32, t = threadIdx.x;
    int nl = t & 31, cr = t >> 5;
    if (t < 32) smu[t] = mu[b * CC + c0 + t];
#pragma unroll
    for (int q = 0; q < 4; ++q)
        tile[cr + q * 8][nl] = x[((size_t)b * CC + c0 + cr + q * 8) * NN + n0 + nl];
    __syncthreads();
    int nr = t >> 3, cq = t & 7;
    uint2 p;
    p.x = (unsigned int)f2bf(tile[cq * 4 + 0][nr]) | ((unsigned int)f2bf(tile[cq * 4 + 1][nr]) << 16);
    p.y = (unsigned int)f2bf(tile[cq * 4 + 2][nr]) | ((unsigned int)f2bf(tile[cq * 4 + 3][nr]) << 16);
    *(uint2*)&xT[((size_t)b * NN + n0 + nr) * CC + c0 + cq * 4] = p;
    int n = t & 31, cseg = t >> 5;
    float part = 0.f;
#pragma unroll
    for (int q = 0; q < 4; ++q) {
        float d = tile[cseg * 4 + q][n] - smu[cseg * 4 + q];
        part += d * d;
    }
    __syncthreads();
    tile[n][cseg] = part;
    __syncthreads();
    if (t < 32) {
        float s = 0.f;
#pragma unroll
        for (int j = 0; j < 8; ++j) s += tile[t][j];
        atomicAdd(&score[(size_t)b * NN + n0 + t], s);
    }
}

// radix-select: per batch, top-1024 set -> idx_s, bottom-1024 set -> idx_g (order arbitrary)
__global__ __launch_bounds__(1024) void select_kernel(const float* __restrict__ score,
                                                      int* __restrict__ idx_s, int* __restrict__ idx_g) {
    int b = blockIdx.x, t = threadIdx.x;
    __shared__ unsigned int keys[NN];
    __shared__ unsigned int hist[256];
    __shared__ unsigned int sbin, skrem;
    __shared__ int outcnt, eqcnt;
    __shared__ int eqidx[NN];
    for (int q = t; q < NN; q += 1024) keys[q] = __float_as_uint(score[(size_t)b * NN + q]);
    __syncthreads();
    for (int r = 0; r < 2; ++r) {
        unsigned int flip = r ? 0xFFFFFFFFu : 0u;
        unsigned int prefix = 0u, pmask = 0u;
        unsigned int k = MM;
        for (int pass = 0; pass < 4; ++pass) {
            int shift = 24 - 8 * pass;
            if (t < 256) hist[t] = 0u;
            __syncthreads();
            for (int q = t; q < NN; q += 1024) {
                unsigned int kv = keys[q] ^ flip;
                if ((kv & pmask) == prefix) atomicAdd(&hist[(kv >> shift) & 255u], 1u);
            }
            __syncthreads();
            for (int off = 1; off < 256; off <<= 1) {
                unsigned int v = 0u;
                if (t < 256) v = hist[t] + ((t + off < 256) ? hist[t + off] : 0u);
                __syncthreads();
                if (t < 256) hist[t] = v;
                __syncthreads();
            }
            if (t < 256) {
                unsigned int sj = hist[t], sj1 = (t < 255) ? hist[t + 1] : 0u;
                if (sj >= k && sj1 < k) { sbin = (unsigned int)t; skrem = k - sj1; }
            }
            __syncthreads();
            prefix |= sbin << shift;
            pmask |= 0xFFu << shift;
            k = skrem;
            __syncthreads();
        }
        unsigned int T = prefix;
        unsigned int krem = k;
        int* outp = r ? idx_g : idx_s;
        if (t == 0) { outcnt = 0; eqcnt = 0; }
        __syncthreads();
        for (int q = t; q < NN; q += 1024) {
            unsigned int kv = keys[q] ^ flip;
            if (kv > T) { int pp = atomicAdd(&outcnt, 1); outp[(size_t)b * MM + pp] = q; }
            else if (kv == T) { int pp = atomicAdd(&eqcnt, 1); eqidx[pp] = q; }
        }
        __syncthreads();
        int ne = eqcnt;
        for (int i = t; i < ne; i += 1024) {
            int me = eqidx[i];
            int rank = 0;
            for (int j = 0; j < ne; ++j) rank += (eqidx[j] < me) ? 1 : 0;
            if (rank < (int)krem) { int pp = atomicAdd(&outcnt, 1); outp[(size_t)b * MM + pp] = me; }
        }
        __syncthreads();
    }
}

__global__ __launch_bounds__(256) void bz_kernel(const float* __restrict__ Wf, const float* __restrict__ bf,
                                                 const float* __restrict__ bo_s, const float* __restrict__ bo_g,
                                                 float* __restrict__ bz) {
    int e = threadIdx.x;
    float acc = bf[e];
    for (int c = 0; c < CC; ++c)
        acc += Wf[e * 2 * CC + c] * bo_s[c] + Wf[e * 2 * CC + CC + c] * bo_g[c];
    bz[e] = acc;
}

__global__ __launch_bounds__(256) void wf12_kernel(const float* __restrict__ Wf, float* __restrict__ Wf12) {
    int e = blockIdx.x, c = threadIdx.x;
    Wf12[e * CC + c] = Wf[e * 2 * CC + c] + Wf[e * 2 * CC + CC + c];
}

// ---- branch precompute, consolidated ----
__global__ __launch_bounds__(256) void prep1_kernel(
    const float* __restrict__ Wo, const float* __restrict__ Wv,
    const float* __restrict__ Wq, const float* __restrict__ Wk,
    const float* __restrict__ bq, const float* __restrict__ bk, const float* __restrict__ bv,
    float* __restrict__ WoWv, unsigned short* __restrict__ W2_16,
    float* __restrict__ wob, float* __restrict__ u, float* __restrict__ b2)
{
    int xr = blockIdx.x, y = blockIdx.y, t = threadIdx.x;
    if (y == 0) {
        __shared__ float arow[CC];
        arow[t] = Wo[xr * CC + t];
        __syncthreads();
        float acc = 0.f;
        for (int k = 0; k < CC; ++k) acc += arow[k] * Wv[k * CC + t];
        WoWv[xr * CC + t] = acc;
    } else if (y == 1) {
        __shared__ float aq[CC];
        aq[t] = Wq[t * CC + xr];
        __syncthreads();
        float acc = 0.f;
        for (int c = 0; c < CC; ++c) acc += aq[c] * Wk[c * CC + t];
        W2_16[xr * CC + t] = f2bf(acc);
    } else if (xr == 0) {
        float a1 = 0.f, a2 = 0.f, a3 = 0.f;
        for (int c = 0; c < CC; ++c) {
            a1 += Wo[t * CC + c] * bv[c];
            a2 += bq[c] * Wk[c * CC + t];
            a3 += Wq[c * CC + t] * bk[c];
        }
        wob[t] = a1; u[t] = a2; b2[t] = a3;
        if (t == 0) { float s = 0.f; for (int c = 0; c < CC; ++c) s += bq[c] * bk[c]; u[CC] = s; }
    }
}

__global__ __launch_bounds__(256) void prep2_kernel(
    const float* __restrict__ Wf, int aoff, const float* __restrict__ WoWv,
    const float* __restrict__ wob, unsigned short* __restrict__ Wvz16, float* __restrict__ bvz)
{
    int e = blockIdx.x, t = threadIdx.x;
    __shared__ float arow[CC];
    __shared__ float red[256];
    arow[t] = Wf[e * 2 * CC + aoff + t];
    __syncthreads();
    float acc = 0.f;
    for (int k = 0; k < CC; ++k) acc += arow[k] * WoWv[k * CC + t];
    Wvz16[e * CC + t] = f2bf(acc);
    red[t] = arow[t] * wob[t];
    __syncthreads();
    for (int w = 128; w > 0; w >>= 1) { if (t < w) red[t] += red[t + w]; __syncthreads(); }
    if (t == 0) bvz[e] = red[0];
}

// beta[row] = Xg[row]·u + u[256]   (one wave per row)
__global__ __launch_bounds__(256) void beta_kernel(const unsigned short* __restrict__ Xg,
                                                   const float* __restrict__ u, float* __restrict__ beta) {
    int row = blockIdx.x * 4 + (threadIdx.x >> 6);
    int l = threadIdx.x & 63;
    uint2 p = *(const uint2*)&Xg[(size_t)row * CC + l * 4];
    float acc = bf2f((unsigned short)(p.x & 0xFFFF)) * u[l * 4]
              + bf2f((unsigned short)(p.x >> 16)) * u[l * 4 + 1]
              + bf2f((unsigned short)(p.y & 0xFFFF)) * u[l * 4 + 2]
              + bf2f((unsigned short)(p.y >> 16)) * u[l * 4 + 3];
    acc += __shfl_xor(acc, 1); acc += __shfl_xor(acc, 2); acc += __shfl_xor(acc, 4);
    acc += __shfl_xor(acc, 8); acc += __shfl_xor(acc, 16); acc += __shfl_xor(acc, 32);
    if (l == 0) beta[row] = acc + u[CC];
}

__global__ __launch_bounds__(256) void conv_bf16_kernel(const float* __restrict__ src,
                                                        unsigned short* __restrict__ dst) {
    int i = blockIdx.x * 256 + threadIdx.x;
    float4 v = *(const float4*)(src + (size_t)i * 4);
    uint2 p;
    p.x = (unsigned int)f2bf(v.x) | ((unsigned int)f2bf(v.y) << 16);
    p.y = (unsigned int)f2bf(v.z) | ((unsigned int)f2bf(v.w) << 16);
    *(uint2*)&dst[(size_t)i * 4] = p;
}

__global__ __launch_bounds__(256) void gather_kernel(const unsigned short* __restrict__ xT,
                                                     const int* __restrict__ idx,
                                                     unsigned short* __restrict__ Xg) {
    int row = blockIdx.x * 4 + (threadIdx.x >> 6);
    int l = threadIdx.x & 63;
    int b = row >> 10, m = row & (MM - 1);
    int src = idx[b * MM + m];
    *(uint2*)&Xg[(size_t)row * CC + l * 4] =
        *(const uint2*)&xT[((size_t)b * NN + src) * CC + l * 4];
}

// ---- generic bf16 MFMA GEMM: out[i][j] = sum_k A[i][k]*Bw[j][k] (+bias), 128x128 tile ----
template<int OMODE>
__global__ __launch_bounds__(256, 3) void gemm_bt(
    const unsigned short* __restrict__ A, size_t a_bs,
    const unsigned short* __restrict__ Bw, size_t b_bs,
    const float* __restrict__ bias,
    void* __restrict__ outp, size_t o_bs, int ldo)
{
    __shared__ __align__(16) unsigned short As[128 * 32];
    __shared__ __align__(16) unsigned short Bs[128 * 32];
    int z = blockIdx.z;
    const unsigned short* Ab = A + z * a_bs + (size_t)blockIdx.x * 128 * CC;
    const unsigned short* Bb = Bw + z * b_bs + (size_t)blockIdx.y * 128 * CC;
    int t = threadIdx.x, w = t >> 6, l = t & 63, g = l >> 4, c16 = l & 15;
    int wi = w >> 1, wj = w & 1;
    int srow = t >> 2, skq = (t & 3) * 8;

    f32x4 acc[4][4];
#pragma unroll
    for (int a = 0; a < 4; ++a)
#pragma unroll
        for (int bq = 0; bq < 4; ++bq) acc[a][bq] = (f32x4){0.f, 0.f, 0.f, 0.f};

    for (int ks = 0; ks < 8; ++ks) {
        int k0 = ks * 32;
        uint4 a0 = *(const uint4*)(Ab + (size_t)srow * CC + k0 + skq);
        uint4 a1 = *(const uint4*)(Ab + (size_t)(srow + 64) * CC + k0 + skq);
        uint4 b0 = *(const uint4*)(Bb + (size_t)srow * CC + k0 + skq);
        uint4 b1 = *(const uint4*)(Bb + (size_t)(srow + 64) * CC + k0 + skq);
        __syncthreads();
        *(uint4*)&As[srow * 32 + skq] = a0;
        *(uint4*)&As[(srow + 64) * 32 + skq] = a1;
        *(uint4*)&Bs[srow * 32 + skq] = b0;
        *(uint4*)&Bs[(srow + 64) * 32 + skq] = b1;
        __syncthreads();
        s16x8 af[4], bf4[4];
#pragma unroll
        for (int fi = 0; fi < 4; ++fi)
            af[fi] = *(const s16x8*)&As[(wi * 64 + fi * 16 + c16) * 32 + g * 8];
#pragma unroll
        for (int fj = 0; fj < 4; ++fj)
            bf4[fj] = *(const s16x8*)&Bs[(wj * 64 + fj * 16 + c16) * 32 + g * 8];
#pragma unroll
        for (int fi = 0; fi < 4; ++fi)
#pragma unroll
            for (int fj = 0; fj < 4; ++fj)
                acc[fi][fj] = __builtin_amdgcn_mfma_f32_16x16x32_bf16(af[fi], bf4[fj], acc[fi][fj], 0, 0, 0);
    }

    int i0 = blockIdx.x * 128 + wi * 64, j0 = blockIdx.y * 128 + wj * 64;
#pragma unroll
    for (int fi = 0; fi < 4; ++fi) {
#pragma unroll
        for (int fj = 0; fj < 4; ++fj) {
            int colg = j0 + fj * 16 + c16;
#pragma unroll
            for (int r = 0; r < 4; ++r) {
                int rowg = i0 + fi * 16 + g * 4 + r;
                float v = acc[fi][fj][r] + (OMODE == 2 ? bias[rowg] : bias[colg]);
                if (OMODE == 0)
                    ((float*)outp)[z * o_bs + (size_t)rowg * ldo + colg] = v;
                else
                    ((unsigned short*)outp)[z * o_bs + (size_t)rowg * ldo + colg] = f2bf(v);
            }
        }
    }
}

// ---- fused flash-style attention: Z[z][n][e] += (exp((xT·K''^T + beta)/16)·V) / rsum[n] ----
// Round-13 structure. do_stats is a RUNTIME flag (wave-uniform scalar branch in the
// epilogue only): round 17 proved two co-compiled template instantiations perturb
// each other's codegen (both dispatches 112->140us, rule #19); single instantiation
// restores stable scheduling. s1p/s2p (16 VGPR) live only in the epilogue where q
// is dead. do_stats=1 on the second (branch-g) dispatch computes BN s1/s2 on final
// Z values -> bn_stats kernel eliminated.
__global__ __attribute__((amdgpu_flat_work_group_size(512, 512)))
__attribute__((amdgpu_waves_per_eu(2, 2)))
void fused_attn(
    const unsigned short* __restrict__ Q,    // xT [B][N][C] bf16
    const unsigned short* __restrict__ K,    // K'' [B][M][C] bf16 (b2 included)
    const unsigned short* __restrict__ Vt,   // [B][C][M] bf16 (bias included)
    const float* __restrict__ beta,          // [B][M]
    float* __restrict__ Z,                   // [B][N][C] +=
    float* __restrict__ bn,                  // [2*CC] atomic += (do_stats=1 only)
    int do_stats)
{
    extern __shared__ __align__(16) unsigned char smem[];
    // [K0 16K][K1 16K][V0 16K][V1 16K][V2 16K][P0 16K][P1 16K][rsl 1K][beta 4K]
    float* rsl = (float*)(smem + 114688);
    float* bs  = (float*)(smem + 115712);
    float* stats = (float*)(smem + 81920);   // reuses P0 region in epilogue

    int z = blockIdx.z;
    int n0 = blockIdx.x * 128;
    int t = threadIdx.x, w = t >> 6, l = t & 63, g = l >> 4, c16 = l & 15;
    int wn = w >> 1, wc = w & 1;   // wave grid: 4 n-rows x 2 m/e-cols

    const unsigned short* Qb = Q + ((size_t)z * NN + n0) * CC;
    const char* Kzb = (const char*)(K + (size_t)z * MM * CC);
    const char* Vzb = (const char*)(Vt + (size_t)z * CC * MM);

    // beta table -> LDS (visible after prologue __syncthreads)
    bs[t] = beta[(size_t)z * MM + t];
    bs[t + 512] = beta[(size_t)z * MM + t + 512];

    // Q fragments: rows wn*32 + fi*16 + c16, k = ks*32 + g*8  (64 VGPR)
    s16x8 q[2][8];
#pragma unroll
    for (int fi = 0; fi < 2; ++fi)
#pragma unroll
        for (int ks = 0; ks < 8; ++ks)
            q[fi][ks] = *(const s16x8*)&Qb[(size_t)(wn * 32 + fi * 16 + c16) * CC + ks * 32 + g * 8];

    f32x4 o[2][8];
#pragma unroll
    for (int fi = 0; fi < 2; ++fi)
#pragma unroll
        for (int fj = 0; fj < 8; ++fj) o[fi][fj] = (f32x4){0.f, 0.f, 0.f, 0.f};
    float rs[2][4];
#pragma unroll
    for (int fi = 0; fi < 2; ++fi)
#pragma unroll
        for (int r = 0; r < 4; ++r) rs[fi][r] = 0.f;

    // gll staging (LDS linear, global source pre-XOR'd). K tile 16KB: 32 rows x 512B.
    auto issueK = [&](int buf, int m0) {
#pragma unroll
        for (int j = 0; j < 2; ++j) {
            int cid = w * 2 + j;
            int row = cid * 2 + (l >> 5);
            int srcoff = ((l & 31) * 16) ^ ((row & 7) << 4);
            const char* gp = Kzb + (size_t)(m0 + row) * 512 + srcoff;
            __builtin_amdgcn_global_load_lds(
                (const __attribute__((address_space(1))) void*)gp,
                (__attribute__((address_space(3))) void*)(smem + buf * 16384 + cid * 1024),
                16, 0, 0);
        }
    };
    // V tile 16KB: 256 rows x 64B; swizzle ^(((row>>1)&3)<<4) — bits 4-5 only (in-row)
    auto issueV = [&](int slot, int m0) {
#pragma unroll
        for (int j = 0; j < 2; ++j) {
            int cid = w * 2 + j;
            int row = cid * 16 + (l >> 2);
            int srcoff = ((l & 3) * 16) ^ (((row >> 1) & 3) << 4);
            const char* gp = Vzb + (size_t)row * 2048 + (size_t)m0 * 2 + srcoff;
            __builtin_amdgcn_global_load_lds(
                (const __attribute__((address_space(1))) void*)gp,
                (__attribute__((address_space(3))) void*)(smem + 32768 + slot * 16384 + cid * 1024),
                16, 0, 0);
        }
    };

    // QK(t)+exp -> P[par]. sacc: n-row = wn*32+fi*16+g*4+r, m = m0 + wc*16 + c16.
    auto qk_exp = [&](int buf, int par, int m0) {
        const unsigned char* Ks = smem + buf * 16384;
        unsigned char* Ps = smem + 81920 + par * 16384;
        f32x4 sacc[2];
#pragma unroll
        for (int fi = 0; fi < 2; ++fi) sacc[fi] = (f32x4){0.f, 0.f, 0.f, 0.f};
        int mr = wc * 16 + c16;
        __builtin_amdgcn_s_setprio(1);
#pragma unroll
        for (int ks = 0; ks < 8; ++ks) {
            s16x8 kf = *(const s16x8*)(Ks + ((mr * 512 + ks * 64 + g * 16) ^ ((mr & 7) << 4)));
#pragma unroll
            for (int fi = 0; fi < 2; ++fi)
                sacc[fi] = __builtin_amdgcn_mfma_f32_16x16x32_bf16(q[fi][ks], kf, sacc[fi], 0, 0, 0);
        }
        __builtin_amdgcn_s_setprio(0);
        float bet = bs[m0 + wc * 16 + c16];
#pragma unroll
        for (int fi = 0; fi < 2; ++fi)
#pragma unroll
            for (int r = 0; r < 4; ++r) {
                float e = __expf((sacc[fi][r] + bet) * SCALE);
                unsigned short h = f2bf(e);
                int nr = wn * 32 + fi * 16 + g * 4 + r;
                *(unsigned short*)(Ps + ((nr * 128 + (wc * 16 + c16) * 2) ^ ((nr & 7) << 4))) = h;
                rs[fi][r] += bf2f(h);
            }
    };
    // PV(t): O += P[par] · V[slot]
    auto pv = [&](int slot, int par) {
        const unsigned char* Vs = smem + 32768 + slot * 16384;
        const unsigned char* Ps = smem + 81920 + par * 16384;
        s16x8 pa[2];
#pragma unroll
        for (int fi = 0; fi < 2; ++fi) {
            int nr = wn * 32 + fi * 16 + c16;
            pa[fi] = *(const s16x8*)(Ps + ((nr * 128 + g * 16) ^ ((nr & 7) << 4)));
        }
        __builtin_amdgcn_s_setprio(1);
#pragma unroll
        for (int fj = 0; fj < 8; ++fj) {
            int er = wc * 128 + fj * 16 + c16;
            s16x8 vb = *(const s16x8*)(Vs + ((er * 64 + g * 16) ^ (((er >> 1) & 3) << 4)));
#pragma unroll
            for (int fi = 0; fi < 2; ++fi)
                o[fi][fj] = __builtin_amdgcn_mfma_f32_16x16x32_bf16(pa[fi], vb, o[fi][fj], 0, 0, 0);
        }
        __builtin_amdgcn_s_setprio(0);
    };

    // prologue: stage tiles 0,1; compute QK(0)->P[0]
    issueK(0, 0); issueV(0, 0);
    issueK(1, 32); issueV(1, 32);
    __syncthreads();
    qk_exp(0, 0, 0);

    for (int mt = 0; mt < 32; ++mt) {
        __syncthreads();   // publishes P[mt&1]; drains gll issued last interval
        if (mt < 30) {
            issueK(mt & 1, (mt + 2) * 32);
            issueV((mt + 2) % 3, (mt + 2) * 32);
        }
        __builtin_amdgcn_sched_barrier(0);
        if (mt < 31) qk_exp((mt + 1) & 1, (mt + 1) & 1, (mt + 1) * 32);
        pv(mt % 3, mt & 1);
    }

    // cross-lane + cross-wave rsum
#pragma unroll
    for (int fi = 0; fi < 2; ++fi)
#pragma unroll
        for (int r = 0; r < 4; ++r) {
            float v = rs[fi][r];
            v += __shfl_xor(v, 1); v += __shfl_xor(v, 2);
            v += __shfl_xor(v, 4); v += __shfl_xor(v, 8);
            if (c16 == 0) rsl[wc * 128 + wn * 32 + fi * 16 + g * 4 + r] = v;
        }
    __syncthreads();
    float* Zb = Z + ((size_t)z * NN + n0) * CC;
    if (!do_stats) {
#pragma unroll
        for (int fi = 0; fi < 2; ++fi)
#pragma unroll
            for (int r = 0; r < 4; ++r) {
                int nr = wn * 32 + fi * 16 + g * 4 + r;
                float inv = 1.0f / (rsl[nr] + rsl[128 + nr]);
#pragma unroll
                for (int fj = 0; fj < 8; ++fj) {
                    int e = wc * 128 + fj * 16 + c16;
                    Zb[(size_t)nr * CC + e] += o[fi][fj][r] * inv;
                }
            }
    } else {
        float s1p[8], s2p[8];
#pragma unroll
        for (int fj = 0; fj < 8; ++fj) { s1p[fj] = 0.f; s2p[fj] = 0.f; }
#pragma unroll
        for (int fi = 0; fi < 2; ++fi)
#pragma unroll
            for (int r = 0; r < 4; ++r) {
                int nr = wn * 32 + fi * 16 + g * 4 + r;
                float inv = 1.0f / (rsl[nr] + rsl[128 + nr]);
#pragma unroll
                for (int fj = 0; fj < 8; ++fj) {
                    int e = wc * 128 + fj * 16 + c16;
                    float fv = Zb[(size_t)nr * CC + e] + o[fi][fj][r] * inv;
                    Zb[(size_t)nr * CC + e] = fv;
                    s1p[fj] += fv;
                    s2p[fj] += fv * fv;
                }
            }
        __syncthreads();                 // P region dead -> reuse as stats
        stats[t] = 0.f;
        __syncthreads();
#pragma unroll
        for (int fj = 0; fj < 8; ++fj) {
            int e = wc * 128 + fj * 16 + c16;
            atomicAdd(&stats[e], s1p[fj]);
            atomicAdd(&stats[256 + e], s2p[fj]);
        }
        __syncthreads();
        if (t < 256) {
            atomicAdd(&bn[t], stats[t]);
            atomicAdd(&bn[CC + t], stats[256 + t]);
        }
    }
}

// normalize + relu + transpose [B][N][C] -> [B][C][N]
__global__ __launch_bounds__(256) void bn_apply_kernel(const float* __restrict__ Z, const float* __restrict__ bn,
                                                       const float* __restrict__ gamma, const float* __restrict__ beta,
                                                       float* __restrict__ out) {
    int b = blockIdx.z, e0 = blockIdx.y * 32, n0 = blockIdx.x * 32, t = threadIdx.x;
    __shared__ float tile[32][33];
    int c = t & 31, r0 = (t >> 5) * 4;
#pragma unroll
    for (int q = 0; q < 4; ++q)
        tile[r0 + q][c] = Z[((size_t)b * NN + n0 + r0 + q) * CC + e0 + c];
    __syncthreads();
    int n = t & 31, er0 = (t >> 5) * 4;
    const float invcnt = 1.0f / (BB * NN);
#pragma unroll
    for (int q = 0; q < 4; ++q) {
        int e = e0 + er0 + q;
        float mean = bn[e] * invcnt;
        float var = bn[CC + e] * invcnt - mean * mean;
        float rsq = rsqrtf(var + EPSV);
        float v = (tile[n][er0 + q] - mean) * rsq * gamma[e] + beta[e];
        out[((size_t)b * CC + e) * NN + n0 + n] = fmaxf(v, 0.f);
    }
}

extern "C" void kernel_launch(void* const* d_in, const int* in_sizes, int n_in,
                              void* d_out, int out_size, void* d_ws, size_t ws_size,
                              hipStream_t stream) {
    const float* x    = (const float*)d_in[0];
    const float* Wq_s = (const float*)d_in[2];  const float* bq_s = (const float*)d_in[3];
    const float* Wk_s = (const float*)d_in[4];  const float* bk_s = (const float*)d_in[5];
    const float* Wv_s = (const float*)d_in[6];  const float* bv_s = (const float*)d_in[7];
    const float* Wo_s = (const float*)d_in[8];  const float* bo_s = (const float*)d_in[9];
    const float* Wq_g = (const float*)d_in[10]; const float* bq_g = (const float*)d_in[11];
    const float* Wk_g = (const float*)d_in[12]; const float* bk_g = (const float*)d_in[13];
    const float* Wv_g = (const float*)d_in[14]; const float* bv_g = (const float*)d_in[15];
    const float* Wo_g = (const float*)d_in[16]; const float* bo_g = (const float*)d_in[17];
    const float* Wf   = (const float*)d_in[18]; const float* bf   = (const float*)d_in[19];
    const float* gamma = (const float*)d_in[20]; const float* beta = (const float*)d_in[21];

    float* ws    = (float*)d_ws;
    float* mu    = ws + OFF_MU;
    float* score = ws + OFF_SCORE;
    int*   idx_s = (int*)(ws + OFF_IDX);
    int*   idx_g = idx_s + BB * MM;
    float* WoWv  = ws + OFF_U;
    float* Wf12  = ws + OFF_WF12;
    float* bvz   = ws + OFF_BVZ;
    float* bz    = ws + OFF_BZ;
    float* uvec  = ws + OFF_MU;            // mu dead after transpose_score; 257 floats
    float* b2    = ws + OFF_MU + 512;
    float* wob   = ws + OFF_MU + 1024;
    float* betaA = ws + OFF_SCORE;         // score dead after select
    unsigned short* Wf12_16 = (unsigned short*)(ws + OFF_W16);
    unsigned short* W2_16   = Wf12_16 + 65536;
    unsigned short* Wvz16   = W2_16 + 65536;
    unsigned short* Xg16 = (unsigned short*)(ws + OFF_XG);
    unsigned short* K16  = (unsigned short*)(ws + OFF_K16);
    unsigned short* Vt16 = (unsigned short*)(ws + OFF_VT16);
    float* Z     = ws + OFF_Z;
    float* bn    = ws + OFF_BN;
    // d_out doubles as scratch: second half holds xT16 (dead before bn_apply writes)
    unsigned short* xT16 = (unsigned short*)d_out + (size_t)BB * NN * CC;

    zero_bn_kernel<<<1, 256, 0, stream>>>(bn);
    mean_kernel<<<dim3(CC, BB), 256, 0, stream>>>(x, mu);
    zero_rsum_kernel<<<BB * NN / 256, 256, 0, stream>>>(score);
    transpose_score_kernel<<<dim3(NN / 32, CC / 32, BB), 256, 0, stream>>>(x, mu, xT16, score);
    select_kernel<<<BB, 1024, 0, stream>>>(score, idx_s, idx_g);
    wf12_kernel<<<CC, 256, 0, stream>>>(Wf, Wf12);
    bz_kernel<<<1, 256, 0, stream>>>(Wf, bf, bo_s, bo_g, bz);
    conv_bf16_kernel<<<64, 256, 0, stream>>>(Wf12, Wf12_16);
    // Z = xT @ Wf12^T + bz  (residual x through both conv halves)
    gemm_bt<0><<<dim3(512, 2, 1), 256, 0, stream>>>(xT16, 0, Wf12_16, 0, bz, Z, 0, CC);

    for (int br = 0; br < 2; ++br) {
        const float* Wo = br ? Wo_g : Wo_s;
        const float* Wv = br ? Wv_g : Wv_s;  const float* bv = br ? bv_g : bv_s;
        const float* Wk = br ? Wk_g : Wk_s;  const float* bk = br ? bk_g : bk_s;
        const float* Wq = br ? Wq_g : Wq_s;  const float* bq = br ? bq_g : bq_s;
        int* idx = br ? idx_g : idx_s;
        int aoff = br ? CC : 0;
        prep1_kernel<<<dim3(CC, 3), 256, 0, stream>>>(Wo, Wv, Wq, Wk, bq, bk, bv,
                                                      WoWv, W2_16, wob, uvec, b2);
        prep2_kernel<<<CC, 256, 0, stream>>>(Wf, aoff, WoWv, wob, Wvz16, bvz);
        gather_kernel<<<BB * MM / 4, 256, 0, stream>>>(xT16, idx, Xg16);
        gemm_bt<1><<<dim3(BB * MM / 128, 2, 1), 256, 0, stream>>>(Xg16, 0, W2_16, 0, b2, K16, 0, CC);
        beta_kernel<<<BB * MM / 4, 256, 0, stream>>>(Xg16, uvec, betaA);
        gemm_bt<2><<<dim3(2, 8, BB), 256, 0, stream>>>(Wvz16, 0, Xg16, (size_t)MM * CC, bvz,
                                                       Vt16, (size_t)CC * MM, MM);

        // fused flash attention; second dispatch also accumulates BN stats (runtime flag)
        fused_attn<<<dim3(NN / 128, 1, BB), 512, 119808, stream>>>(
            xT16, K16, Vt16, betaA, Z, bn, br);
    }

    bn_apply_kernel<<<dim3(NN / 32, CC / 32, BB), 256, 0, stream>>>(Z, bn, gamma, beta, (float*)d_out);
}

// Round 19
// 598.980 us; speedup vs baseline: 1.0134x; 1.0134x over previous
//
#include <hip/hip_runtime.h>

#define BB 16
#define CC 256
#define NN 4096
#define MM 1024
#define EPSV 1e-5f
#define SCALE (1.0f/16.0f)   // 1/sqrt(C)

// ---- workspace layout (float offsets). ----
#define OFF_MU    0            // 4096  (musum; dead after score_fix -> u[257], b2, wob)
#define OFF_SCORE 4096         // 65536 (s2/score; dead after select -> beta)
#define OFF_IDX   69632        // 32768 ints (idx_s then idx_g)
#define OFF_U     102400       // 65536 (WoWv f32 scratch)
#define OFF_WF12  233472       // 65536 (Wf12 f32)
#define OFF_BVZ   299008       // 256
#define OFF_BZ    299264       // 256
#define OFF_W16   299520       // 4 bf16 weight mats = 131072 floats
#define OFF_XG    430592       // Xg bf16 [16*1024][256] = 2097152 floats
#define OFF_K16   2527744      // K'' bf16 = 2097152 floats
#define OFF_VT16  4624896      // Vt bf16 = 2097152 floats
#define OFF_Z     6722048      // 16777216 floats
#define OFF_BN    23499264     // 512

typedef __attribute__((ext_vector_type(8))) short s16x8;
typedef __attribute__((ext_vector_type(4))) float f32x4;

__device__ __forceinline__ unsigned short f2bf(float f) {
    unsigned int u = __float_as_uint(f);
    return (unsigned short)((u + 0x7FFFu + ((u >> 16) & 1u)) >> 16);
}
__device__ __forceinline__ float bf2f(unsigned short h) {
    return __uint_as_float(((unsigned int)h) << 16);
}

__global__ __launch_bounds__(256) void zero_bn_kernel(float* bn) {
    int t = threadIdx.x;
    bn[t] = 0.f; bn[t + CC] = 0.f;
}

__global__ __launch_bounds__(256) void zero_rsum_kernel(float* r) {
    r[blockIdx.x * 256 + threadIdx.x] = 0.f;
}

// x [B][C][N] f32 -> xT16 [B][N][C] bf16, fused with s2[b,n]=sum_c x^2 and
// musum[b,c]=sum_n x accumulation (mean_kernel's full 256MB x re-read eliminated;
// score finalized by score_fix: score = s2 - (2/N)*xT·musum; the +||mu||^2 term
// is per-batch constant -> top-k invariant).
__global__ __launch_bounds__(256) void transpose_s2_kernel(const float* __restrict__ x,
                                                           unsigned short* __restrict__ xT,
                                                           float* __restrict__ score,
                                                           float* __restrict__ musum) {
    __shared__ float tile[32][33];
    int b = blockIdx.z, c0 = blockIdx.y * 32, n0 = blockIdx.x * 32, t = threadIdx.x;
    int nl = t & 31, cr = t >> 5;
#pragma unroll
    for (int q = 0; q < 4; ++q)
        tile[cr + q * 8][nl] = x[((size_t)b * CC + c0 + cr + q * 8) * NN + n0 + nl];
    __syncthreads();
    int nr = t >> 3, cq = t & 7;
    uint2 p;
    p.x = (unsigned int)f2bf(tile[cq * 4 + 0][nr]) | ((unsigned int)f2bf(tile[cq * 4 + 1][nr]) << 16);
    p.y = (unsigned int)f2bf(tile[cq * 4 + 2][nr]) | ((unsigned int)f2bf(tile[cq * 4 + 3][nr]) << 16);
    *(uint2*)&xT[((size_t)b * NN + n0 + nr) * CC + c0 + cq * 4] = p;
    // partials: a = t&31, seg = t>>5
    int a = t & 31, seg = t >> 5;
    float ps2 = 0.f, pmu = 0.f;
#pragma unroll
    for (int q = 0; q < 4; ++q) {
        float v = tile[seg * 4 + q][a];   // a = n, rows seg*4+q = c
        ps2 += v * v;
        pmu += tile[a][seg * 4 + q];      // a = c, cols = n
    }
    __syncthreads();
    tile[a][seg] = ps2;        // row a(=n), cols 0..7
    tile[a][8 + seg] = pmu;    // row a(=c), cols 8..15
    __syncthreads();
    if (t < 32) {
        float s = 0.f;
#pragma unroll
        for (int j = 0; j < 8; ++j) s += tile[t][j];
        atomicAdd(&score[(size_t)b * NN + n0 + t], s);
    } else if (t < 64) {
        int r = t - 32;
        float s = 0.f;
#pragma unroll
        for (int j = 0; j < 8; ++j) s += tile[r][8 + j];
        atomicAdd(&musum[b * CC + c0 + r], s);
    }
}

// score[row] -= (2/N) * xT[row]·musum[b]   (one wave per row)
__global__ __launch_bounds__(256) void score_fix_kernel(const unsigned short* __restrict__ xT,
                                                        const float* __restrict__ musum,
                                                        float* __restrict__ score) {
    int row = blockIdx.x * 4 + (threadIdx.x >> 6);
    int l = threadIdx.x & 63;
    int b = row >> 12;
    uint2 p = *(const uint2*)&xT[(size_t)row * CC + l * 4];
    const float* ms = musum + b * CC + l * 4;
    float acc = bf2f((unsigned short)(p.x & 0xFFFF)) * ms[0]
              + bf2f((unsigned short)(p.x >> 16)) * ms[1]
              + bf2f((unsigned short)(p.y & 0xFFFF)) * ms[2]
              + bf2f((unsigned short)(p.y >> 16)) * ms[3];
    acc += __shfl_xor(acc, 1); acc += __shfl_xor(acc, 2); acc += __shfl_xor(acc, 4);
    acc += __shfl_xor(acc, 8); acc += __shfl_xor(acc, 16); acc += __shfl_xor(acc, 32);
    if (l == 0) score[row] -= acc * (2.0f / NN);
}

// radix-select: per batch, top-1024 set -> idx_s, bottom-1024 set -> idx_g (order arbitrary)
__global__ __launch_bounds__(1024) void select_kernel(const float* __restrict__ score,
                                                      int* __restrict__ idx_s, int* __restrict__ idx_g) {
    int b = blockIdx.x, t = threadIdx.x;
    __shared__ unsigned int keys[NN];
    __shared__ unsigned int hist[256];
    __shared__ unsigned int sbin, skrem;
    __shared__ int outcnt, eqcnt;
    __shared__ int eqidx[NN];
    for (int q = t; q < NN; q += 1024) keys[q] = __float_as_uint(score[(size_t)b * NN + q]);
    __syncthreads();
    for (int r = 0; r < 2; ++r) {
        unsigned int flip = r ? 0xFFFFFFFFu : 0u;
        unsigned int prefix = 0u, pmask = 0u;
        unsigned int k = MM;
        for (int pass = 0; pass < 4; ++pass) {
            int shift = 24 - 8 * pass;
            if (t < 256) hist[t] = 0u;
            __syncthreads();
            for (int q = t; q < NN; q += 1024) {
                unsigned int kv = keys[q] ^ flip;
                if ((kv & pmask) == prefix) atomicAdd(&hist[(kv >> shift) & 255u], 1u);
            }
            __syncthreads();
            for (int off = 1; off < 256; off <<= 1) {
                unsigned int v = 0u;
                if (t < 256) v = hist[t] + ((t + off < 256) ? hist[t + off] : 0u);
                __syncthreads();
                if (t < 256) hist[t] = v;
                __syncthreads();
            }
            if (t < 256) {
                unsigned int sj = hist[t], sj1 = (t < 255) ? hist[t + 1] : 0u;
                if (sj >= k && sj1 < k) { sbin = (unsigned int)t; skrem = k - sj1; }
            }
            __syncthreads();
            prefix |= sbin << shift;
            pmask |= 0xFFu << shift;
            k = skrem;
            __syncthreads();
        }
        unsigned int T = prefix;
        unsigned int krem = k;
        int* outp = r ? idx_g : idx_s;
        if (t == 0) { outcnt = 0; eqcnt = 0; }
        __syncthreads();
        for (int q = t; q < NN; q += 1024) {
            unsigned int kv = keys[q] ^ flip;
            if (kv > T) { int pp = atomicAdd(&outcnt, 1); outp[(size_t)b * MM + pp] = q; }
            else if (kv == T) { int pp = atomicAdd(&eqcnt, 1); eqidx[pp] = q; }
        }
        __syncthreads();
        int ne = eqcnt;
        for (int i = t; i < ne; i += 1024) {
            int me = eqidx[i];
            int rank = 0;
            for (int j = 0; j < ne; ++j) rank += (eqidx[j] < me) ? 1 : 0;
            if (rank < (int)krem) { int pp = atomicAdd(&outcnt, 1); outp[(size_t)b * MM + pp] = me; }
        }
        __syncthreads();
    }
}

__global__ __launch_bounds__(256) void bz_kernel(const float* __restrict__ Wf, const float* __restrict__ bf,
                                                 const float* __restrict__ bo_s, const float* __restrict__ bo_g,
                                                 float* __restrict__ bz) {
    int e = threadIdx.x;
    float acc = bf[e];
    for (int c = 0; c < CC; ++c)
        acc += Wf[e * 2 * CC + c] * bo_s[c] + Wf[e * 2 * CC + CC + c] * bo_g[c];
    bz[e] = acc;
}

__global__ __launch_bounds__(256) void wf12_kernel(const float* __restrict__ Wf, float* __restrict__ Wf12) {
    int e = blockIdx.x, c = threadIdx.x;
    Wf12[e * CC + c] = Wf[e * 2 * CC + c] + Wf[e * 2 * CC + CC + c];
}

// ---- branch precompute, consolidated ----
__global__ __launch_bounds__(256) void prep1_kernel(
    const float* __restrict__ Wo, const float* __restrict__ Wv,
    const float* __restrict__ Wq, const float* __restrict__ Wk,
    const float* __restrict__ bq, const float* __restrict__ bk, const float* __restrict__ bv,
    float* __restrict__ WoWv, unsigned short* __restrict__ W2_16,
    float* __restrict__ wob, float* __restrict__ u, float* __restrict__ b2)
{
    int xr = blockIdx.x, y = blockIdx.y, t = threadIdx.x;
    if (y == 0) {
        __shared__ float arow[CC];
        arow[t] = Wo[xr * CC + t];
        __syncthreads();
        float acc = 0.f;
        for (int k = 0; k < CC; ++k) acc += arow[k] * Wv[k * CC + t];
        WoWv[xr * CC + t] = acc;
    } else if (y == 1) {
        __shared__ float aq[CC];
        aq[t] = Wq[t * CC + xr];
        __syncthreads();
        float acc = 0.f;
        for (int c = 0; c < CC; ++c) acc += aq[c] * Wk[c * CC + t];
        W2_16[xr * CC + t] = f2bf(acc);
    } else if (xr == 0) {
        float a1 = 0.f, a2 = 0.f, a3 = 0.f;
        for (int c = 0; c < CC; ++c) {
            a1 += Wo[t * CC + c] * bv[c];
            a2 += bq[c] * Wk[c * CC + t];
            a3 += Wq[c * CC + t] * bk[c];
        }
        wob[t] = a1; u[t] = a2; b2[t] = a3;
        if (t == 0) { float s = 0.f; for (int c = 0; c < CC; ++c) s += bq[c] * bk[c]; u[CC] = s; }
    }
}

__global__ __launch_bounds__(256) void prep2_kernel(
    const float* __restrict__ Wf, int aoff, const float* __restrict__ WoWv,
    const float* __restrict__ wob, unsigned short* __restrict__ Wvz16, float* __restrict__ bvz)
{
    int e = blockIdx.x, t = threadIdx.x;
    __shared__ float arow[CC];
    __shared__ float red[256];
    arow[t] = Wf[e * 2 * CC + aoff + t];
    __syncthreads();
    float acc = 0.f;
    for (int k = 0; k < CC; ++k) acc += arow[k] * WoWv[k * CC + t];
    Wvz16[e * CC + t] = f2bf(acc);
    red[t] = arow[t] * wob[t];
    __syncthreads();
    for (int w = 128; w > 0; w >>= 1) { if (t < w) red[t] += red[t + w]; __syncthreads(); }
    if (t == 0) bvz[e] = red[0];
}

// beta[row] = Xg[row]·u + u[256]   (one wave per row)
__global__ __launch_bounds__(256) void beta_kernel(const unsigned short* __restrict__ Xg,
                                                   const float* __restrict__ u, float* __restrict__ beta) {
    int row = blockIdx.x * 4 + (threadIdx.x >> 6);
    int l = threadIdx.x & 63;
    uint2 p = *(const uint2*)&Xg[(size_t)row * CC + l * 4];
    float acc = bf2f((unsigned short)(p.x & 0xFFFF)) * u[l * 4]
              + bf2f((unsigned short)(p.x >> 16)) * u[l * 4 + 1]
              + bf2f((unsigned short)(p.y & 0xFFFF)) * u[l * 4 + 2]
              + bf2f((unsigned short)(p.y >> 16)) * u[l * 4 + 3];
    acc += __shfl_xor(acc, 1); acc += __shfl_xor(acc, 2); acc += __shfl_xor(acc, 4);
    acc += __shfl_xor(acc, 8); acc += __shfl_xor(acc, 16); acc += __shfl_xor(acc, 32);
    if (l == 0) beta[row] = acc + u[CC];
}

__global__ __launch_bounds__(256) void conv_bf16_kernel(const float* __restrict__ src,
                                                        unsigned short* __restrict__ dst) {
    int i = blockIdx.x * 256 + threadIdx.x;
    float4 v = *(const float4*)(src + (size_t)i * 4);
    uint2 p;
    p.x = (unsigned int)f2bf(v.x) | ((unsigned int)f2bf(v.y) << 16);
    p.y = (unsigned int)f2bf(v.z) | ((unsigned int)f2bf(v.w) << 16);
    *(uint2*)&dst[(size_t)i * 4] = p;
}

__global__ __launch_bounds__(256) void gather_kernel(const unsigned short* __restrict__ xT,
                                                     const int* __restrict__ idx,
                                                     unsigned short* __restrict__ Xg) {
    int row = blockIdx.x * 4 + (threadIdx.x >> 6);
    int l = threadIdx.x & 63;
    int b = row >> 10, m = row & (MM - 1);
    int src = idx[b * MM + m];
    *(uint2*)&Xg[(size_t)row * CC + l * 4] =
        *(const uint2*)&xT[((size_t)b * NN + src) * CC + l * 4];
}

// ---- generic bf16 MFMA GEMM: out[i][j] = sum_k A[i][k]*Bw[j][k] (+bias), 128x128 tile ----
template<int OMODE>
__global__ __launch_bounds__(256, 3) void gemm_bt(
    const unsigned short* __restrict__ A, size_t a_bs,
    const unsigned short* __restrict__ Bw, size_t b_bs,
    const float* __restrict__ bias,
    void* __restrict__ outp, size_t o_bs, int ldo)
{
    __shared__ __align__(16) unsigned short As[128 * 32];
    __shared__ __align__(16) unsigned short Bs[128 * 32];
    int z = blockIdx.z;
    const unsigned short* Ab = A + z * a_bs + (size_t)blockIdx.x * 128 * CC;
    const unsigned short* Bb = Bw + z * b_bs + (size_t)blockIdx.y * 128 * CC;
    int t = threadIdx.x, w = t >> 6, l = t & 63, g = l >> 4, c16 = l & 15;
    int wi = w >> 1, wj = w & 1;
    int srow = t >> 2, skq = (t & 3) * 8;

    f32x4 acc[4][4];
#pragma unroll
    for (int a = 0; a < 4; ++a)
#pragma unroll
        for (int bq = 0; bq < 4; ++bq) acc[a][bq] = (f32x4){0.f, 0.f, 0.f, 0.f};

    for (int ks = 0; ks < 8; ++ks) {
        int k0 = ks * 32;
        uint4 a0 = *(const uint4*)(Ab + (size_t)srow * CC + k0 + skq);
        uint4 a1 = *(const uint4*)(Ab + (size_t)(srow + 64) * CC + k0 + skq);
        uint4 b0 = *(const uint4*)(Bb + (size_t)srow * CC + k0 + skq);
        uint4 b1 = *(const uint4*)(Bb + (size_t)(srow + 64) * CC + k0 + skq);
        __syncthreads();
        *(uint4*)&As[srow * 32 + skq] = a0;
        *(uint4*)&As[(srow + 64) * 32 + skq] = a1;
        *(uint4*)&Bs[srow * 32 + skq] = b0;
        *(uint4*)&Bs[(srow + 64) * 32 + skq] = b1;
        __syncthreads();
        s16x8 af[4], bf4[4];
#pragma unroll
        for (int fi = 0; fi < 4; ++fi)
            af[fi] = *(const s16x8*)&As[(wi * 64 + fi * 16 + c16) * 32 + g * 8];
#pragma unroll
        for (int fj = 0; fj < 4; ++fj)
            bf4[fj] = *(const s16x8*)&Bs[(wj * 64 + fj * 16 + c16) * 32 + g * 8];
#pragma unroll
        for (int fi = 0; fi < 4; ++fi)
#pragma unroll
            for (int fj = 0; fj < 4; ++fj)
                acc[fi][fj] = __builtin_amdgcn_mfma_f32_16x16x32_bf16(af[fi], bf4[fj], acc[fi][fj], 0, 0, 0);
    }

    int i0 = blockIdx.x * 128 + wi * 64, j0 = blockIdx.y * 128 + wj * 64;
#pragma unroll
    for (int fi = 0; fi < 4; ++fi) {
#pragma unroll
        for (int fj = 0; fj < 4; ++fj) {
            int colg = j0 + fj * 16 + c16;
#pragma unroll
            for (int r = 0; r < 4; ++r) {
                int rowg = i0 + fi * 16 + g * 4 + r;
                float v = acc[fi][fj][r] + (OMODE == 2 ? bias[rowg] : bias[colg]);
                if (OMODE == 0)
                    ((float*)outp)[z * o_bs + (size_t)rowg * ldo + colg] = v;
                else
                    ((unsigned short*)outp)[z * o_bs + (size_t)rowg * ldo + colg] = f2bf(v);
            }
        }
    }
}

// ---- fused flash-style attention: Z[z][n][e] += (exp((xT·K''^T + beta)/16)·V) / rsum[n] ----
// EXACT round-13 shape (112us/dispatch, no spill, VGPR=104). r17/r18 showed ANY
// stats-epilogue addition (template or runtime flag) perturbs the main loop to 140us;
// BN stats stay in the separate bn_stats kernel.
__global__ __attribute__((amdgpu_flat_work_group_size(512, 512)))
__attribute__((amdgpu_waves_per_eu(2, 2)))
void fused_attn(
    const unsigned short* __restrict__ Q,    // xT [B][N][C] bf16
    const unsigned short* __restrict__ K,    // K'' [B][M][C] bf16 (b2 included)
    const unsigned short* __restrict__ Vt,   // [B][C][M] bf16 (bias included)
    const float* __restrict__ beta,          // [B][M]
    float* __restrict__ Z)                   // [B][N][C] +=
{
    extern __shared__ __align__(16) unsigned char smem[];
    // [K0 16K][K1 16K][V0 16K][V1 16K][V2 16K][P0 16K][P1 16K][rsl 1K][beta 4K]
    float* rsl = (float*)(smem + 114688);
    float* bs  = (float*)(smem + 115712);

    int z = blockIdx.z;
    int n0 = blockIdx.x * 128;
    int t = threadIdx.x, w = t >> 6, l = t & 63, g = l >> 4, c16 = l & 15;
    int wn = w >> 1, wc = w & 1;   // wave grid: 4 n-rows x 2 m/e-cols

    const unsigned short* Qb = Q + ((size_t)z * NN + n0) * CC;
    const char* Kzb = (const char*)(K + (size_t)z * MM * CC);
    const char* Vzb = (const char*)(Vt + (size_t)z * CC * MM);

    // beta table -> LDS (visible after prologue __syncthreads)
    bs[t] = beta[(size_t)z * MM + t];
    bs[t + 512] = beta[(size_t)z * MM + t + 512];

    // Q fragments: rows wn*32 + fi*16 + c16, k = ks*32 + g*8  (64 VGPR)
    s16x8 q[2][8];
#pragma unroll
    for (int fi = 0; fi < 2; ++fi)
#pragma unroll
        for (int ks = 0; ks < 8; ++ks)
            q[fi][ks] = *(const s16x8*)&Qb[(size_t)(wn * 32 + fi * 16 + c16) * CC + ks * 32 + g * 8];

    f32x4 o[2][8];
#pragma unroll
    for (int fi = 0; fi < 2; ++fi)
#pragma unroll
        for (int fj = 0; fj < 8; ++fj) o[fi][fj] = (f32x4){0.f, 0.f, 0.f, 0.f};
    float rs[2][4];
#pragma unroll
    for (int fi = 0; fi < 2; ++fi)
#pragma unroll
        for (int r = 0; r < 4; ++r) rs[fi][r] = 0.f;

    // gll staging (LDS linear, global source pre-XOR'd). K tile 16KB: 32 rows x 512B.
    auto issueK = [&](int buf, int m0) {
#pragma unroll
        for (int j = 0; j < 2; ++j) {
            int cid = w * 2 + j;
            int row = cid * 2 + (l >> 5);
            int srcoff = ((l & 31) * 16) ^ ((row & 7) << 4);
            const char* gp = Kzb + (size_t)(m0 + row) * 512 + srcoff;
            __builtin_amdgcn_global_load_lds(
                (const __attribute__((address_space(1))) void*)gp,
                (__attribute__((address_space(3))) void*)(smem + buf * 16384 + cid * 1024),
                16, 0, 0);
        }
    };
    // V tile 16KB: 256 rows x 64B; swizzle ^(((row>>1)&3)<<4) — bits 4-5 only (in-row)
    auto issueV = [&](int slot, int m0) {
#pragma unroll
        for (int j = 0; j < 2; ++j) {
            int cid = w * 2 + j;
            int row = cid * 16 + (l >> 2);
            int srcoff = ((l & 3) * 16) ^ (((row >> 1) & 3) << 4);
            const char* gp = Vzb + (size_t)row * 2048 + (size_t)m0 * 2 + srcoff;
            __builtin_amdgcn_global_load_lds(
                (const __attribute__((address_space(1))) void*)gp,
                (__attribute__((address_space(3))) void*)(smem + 32768 + slot * 16384 + cid * 1024),
                16, 0, 0);
        }
    };

    // QK(t)+exp -> P[par]. sacc: n-row = wn*32+fi*16+g*4+r, m = m0 + wc*16 + c16.
    auto qk_exp = [&](int buf, int par, int m0) {
        const unsigned char* Ks = smem + buf * 16384;
        unsigned char* Ps = smem + 81920 + par * 16384;
        f32x4 sacc[2];
#pragma unroll
        for (int fi = 0; fi < 2; ++fi) sacc[fi] = (f32x4){0.f, 0.f, 0.f, 0.f};
        int mr = wc * 16 + c16;
        __builtin_amdgcn_s_setprio(1);
#pragma unroll
        for (int ks = 0; ks < 8; ++ks) {
            s16x8 kf = *(const s16x8*)(Ks + ((mr * 512 + ks * 64 + g * 16) ^ ((mr & 7) << 4)));
#pragma unroll
            for (int fi = 0; fi < 2; ++fi)
                sacc[fi] = __builtin_amdgcn_mfma_f32_16x16x32_bf16(q[fi][ks], kf, sacc[fi], 0, 0, 0);
        }
        __builtin_amdgcn_s_setprio(0);
        float bet = bs[m0 + wc * 16 + c16];
#pragma unroll
        for (int fi = 0; fi < 2; ++fi)
#pragma unroll
            for (int r = 0; r < 4; ++r) {
                float e = __expf((sacc[fi][r] + bet) * SCALE);
                unsigned short h = f2bf(e);
                int nr = wn * 32 + fi * 16 + g * 4 + r;
                *(unsigned short*)(Ps + ((nr * 128 + (wc * 16 + c16) * 2) ^ ((nr & 7) << 4))) = h;
                rs[fi][r] += bf2f(h);
            }
    };
    // PV(t): O += P[par] · V[slot]
    auto pv = [&](int slot, int par) {
        const unsigned char* Vs = smem + 32768 + slot * 16384;
        const unsigned char* Ps = smem + 81920 + par * 16384;
        s16x8 pa[2];
#pragma unroll
        for (int fi = 0; fi < 2; ++fi) {
            int nr = wn * 32 + fi * 16 + c16;
            pa[fi] = *(const s16x8*)(Ps + ((nr * 128 + g * 16) ^ ((nr & 7) << 4)));
        }
        __builtin_amdgcn_s_setprio(1);
#pragma unroll
        for (int fj = 0; fj < 8; ++fj) {
            int er = wc * 128 + fj * 16 + c16;
            s16x8 vb = *(const s16x8*)(Vs + ((er * 64 + g * 16) ^ (((er >> 1) & 3) << 4)));
#pragma unroll
            for (int fi = 0; fi < 2; ++fi)
                o[fi][fj] = __builtin_amdgcn_mfma_f32_16x16x32_bf16(pa[fi], vb, o[fi][fj], 0, 0, 0);
        }
        __builtin_amdgcn_s_setprio(0);
    };

    // prologue: stage tiles 0,1; compute QK(0)->P[0]
    issueK(0, 0); issueV(0, 0);
    issueK(1, 32); issueV(1, 32);
    __syncthreads();
    qk_exp(0, 0, 0);

    for (int mt = 0; mt < 32; ++mt) {
        __syncthreads();   // publishes P[mt&1]; drains gll issued last interval
        if (mt < 30) {
            issueK(mt & 1, (mt + 2) * 32);
            issueV((mt + 2) % 3, (mt + 2) * 32);
        }
        __builtin_amdgcn_sched_barrier(0);
        if (mt < 31) qk_exp((mt + 1) & 1, (mt + 1) & 1, (mt + 1) * 32);
        pv(mt % 3, mt & 1);
    }

    // cross-lane + cross-wave rsum
#pragma unroll
    for (int fi = 0; fi < 2; ++fi)
#pragma unroll
        for (int r = 0; r < 4; ++r) {
            float v = rs[fi][r];
            v += __shfl_xor(v, 1); v += __shfl_xor(v, 2);
            v += __shfl_xor(v, 4); v += __shfl_xor(v, 8);
            if (c16 == 0) rsl[wc * 128 + wn * 32 + fi * 16 + g * 4 + r] = v;
        }
    __syncthreads();
    float* Zb = Z + ((size_t)z * NN + n0) * CC;
#pragma unroll
    for (int fi = 0; fi < 2; ++fi)
#pragma unroll
        for (int r = 0; r < 4; ++r) {
            int nr = wn * 32 + fi * 16 + g * 4 + r;
            float inv = 1.0f / (rsl[nr] + rsl[128 + nr]);
#pragma unroll
            for (int fj = 0; fj < 8; ++fj) {
                int e = wc * 128 + fj * 16 + c16;
                Zb[(size_t)nr * CC + e] += o[fi][fj][r] * inv;
            }
        }
}

// BN stats: per-channel sum and sumsq over B*N rows of Z [B*N][C]
__global__ __launch_bounds__(256) void bn_stats_kernel(const float* __restrict__ Z, float* __restrict__ bn) {
    int blk = blockIdx.x, e = threadIdx.x;
    const float* p = Z + (size_t)blk * 256 * CC + e;
    float s1 = 0.f, s2 = 0.f;
    for (int r = 0; r < 256; ++r) { float v = p[(size_t)r * CC]; s1 += v; s2 += v * v; }
    atomicAdd(&bn[e], s1);
    atomicAdd(&bn[CC + e], s2);
}

// normalize + relu + transpose [B][N][C] -> [B][C][N]
__global__ __launch_bounds__(256) void bn_apply_kernel(const float* __restrict__ Z, const float* __restrict__ bn,
                                                       const float* __restrict__ gamma, const float* __restrict__ beta,
                                                       float* __restrict__ out) {
    int b = blockIdx.z, e0 = blockIdx.y * 32, n0 = blockIdx.x * 32, t = threadIdx.x;
    __shared__ float tile[32][33];
    int c = t & 31, r0 = (t >> 5) * 4;
#pragma unroll
    for (int q = 0; q < 4; ++q)
        tile[r0 + q][c] = Z[((size_t)b * NN + n0 + r0 + q) * CC + e0 + c];
    __syncthreads();
    int n = t & 31, er0 = (t >> 5) * 4;
    const float invcnt = 1.0f / (BB * NN);
#pragma unroll
    for (int q = 0; q < 4; ++q) {
        int e = e0 + er0 + q;
        float mean = bn[e] * invcnt;
        float var = bn[CC + e] * invcnt - mean * mean;
        float rsq = rsqrtf(var + EPSV);
        float v = (tile[n][er0 + q] - mean) * rsq * gamma[e] + beta[e];
        out[((size_t)b * CC + e) * NN + n0 + n] = fmaxf(v, 0.f);
    }
}

extern "C" void kernel_launch(void* const* d_in, const int* in_sizes, int n_in,
                              void* d_out, int out_size, void* d_ws, size_t ws_size,
                              hipStream_t stream) {
    const float* x    = (const float*)d_in[0];
    const float* Wq_s = (const float*)d_in[2];  const float* bq_s = (const float*)d_in[3];
    const float* Wk_s = (const float*)d_in[4];  const float* bk_s = (const float*)d_in[5];
    const float* Wv_s = (const float*)d_in[6];  const float* bv_s = (const float*)d_in[7];
    const float* Wo_s = (const float*)d_in[8];  const float* bo_s = (const float*)d_in[9];
    const float* Wq_g = (const float*)d_in[10]; const float* bq_g = (const float*)d_in[11];
    const float* Wk_g = (const float*)d_in[12]; const float* bk_g = (const float*)d_in[13];
    const float* Wv_g = (const float*)d_in[14]; const float* bv_g = (const float*)d_in[15];
    const float* Wo_g = (const float*)d_in[16]; const float* bo_g = (const float*)d_in[17];
    const float* Wf   = (const float*)d_in[18]; const float* bf   = (const float*)d_in[19];
    const float* gamma = (const float*)d_in[20]; const float* beta = (const float*)d_in[21];

    float* ws    = (float*)d_ws;
    float* musum = ws + OFF_MU;
    float* score = ws + OFF_SCORE;
    int*   idx_s = (int*)(ws + OFF_IDX);
    int*   idx_g = idx_s + BB * MM;
    float* WoWv  = ws + OFF_U;
    float* Wf12  = ws + OFF_WF12;
    float* bvz   = ws + OFF_BVZ;
    float* bz    = ws + OFF_BZ;
    float* uvec  = ws + OFF_MU;            // musum dead after score_fix; 257 floats
    float* b2    = ws + OFF_MU + 512;
    float* wob   = ws + OFF_MU + 1024;
    float* betaA = ws + OFF_SCORE;         // score dead after select
    unsigned short* Wf12_16 = (unsigned short*)(ws + OFF_W16);
    unsigned short* W2_16   = Wf12_16 + 65536;
    unsigned short* Wvz16   = W2_16 + 65536;
    unsigned short* Xg16 = (unsigned short*)(ws + OFF_XG);
    unsigned short* K16  = (unsigned short*)(ws + OFF_K16);
    unsigned short* Vt16 = (unsigned short*)(ws + OFF_VT16);
    float* Z     = ws + OFF_Z;
    float* bn    = ws + OFF_BN;
    // d_out doubles as scratch: second half holds xT16 (dead before bn_apply writes)
    unsigned short* xT16 = (unsigned short*)d_out + (size_t)BB * NN * CC;

    zero_bn_kernel<<<1, 256, 0, stream>>>(bn);
    // zero musum (4096) + score (65536): contiguous at ws[0 .. 69632)
    zero_rsum_kernel<<<272, 256, 0, stream>>>(ws);
    transpose_s2_kernel<<<dim3(NN / 32, CC / 32, BB), 256, 0, stream>>>(x, xT16, score, musum);
    score_fix_kernel<<<BB * NN / 4, 256, 0, stream>>>(xT16, musum, score);
    select_kernel<<<BB, 1024, 0, stream>>>(score, idx_s, idx_g);
    wf12_kernel<<<CC, 256, 0, stream>>>(Wf, Wf12);
    bz_kernel<<<1, 256, 0, stream>>>(Wf, bf, bo_s, bo_g, bz);
    conv_bf16_kernel<<<64, 256, 0, stream>>>(Wf12, Wf12_16);
    // Z = xT @ Wf12^T + bz  (residual x through both conv halves)
    gemm_bt<0><<<dim3(512, 2, 1), 256, 0, stream>>>(xT16, 0, Wf12_16, 0, bz, Z, 0, CC);

    for (int br = 0; br < 2; ++br) {
        const float* Wo = br ? Wo_g : Wo_s;
        const float* Wv = br ? Wv_g : Wv_s;  const float* bv = br ? bv_g : bv_s;
        const float* Wk = br ? Wk_g : Wk_s;  const float* bk = br ? bk_g : bk_s;
        const float* Wq = br ? Wq_g : Wq_s;  const float* bq = br ? bq_g : bq_s;
        int* idx = br ? idx_g : idx_s;
        int aoff = br ? CC : 0;
        prep1_kernel<<<dim3(CC, 3), 256, 0, stream>>>(Wo, Wv, Wq, Wk, bq, bk, bv,
                                                      WoWv, W2_16, wob, uvec, b2);
        prep2_kernel<<<CC, 256, 0, stream>>>(Wf, aoff, WoWv, wob, Wvz16, bvz);
        gather_kernel<<<BB * MM / 4, 256, 0, stream>>>(xT16, idx, Xg16);
        gemm_bt<1><<<dim3(BB * MM / 128, 2, 1), 256, 0, stream>>>(Xg16, 0, W2_16, 0, b2, K16, 0, CC);
        beta_kernel<<<BB * MM / 4, 256, 0, stream>>>(Xg16, uvec, betaA);
        gemm_bt<2><<<dim3(2, 8, BB), 256, 0, stream>>>(Wvz16, 0, Xg16, (size_t)MM * CC, bvz,
                                                       Vt16, (size_t)CC * MM, MM);

        // fused flash attention: Z += softmax((xT·K''^T + beta)/16)·V
        fused_attn<<<dim3(NN / 128, 1, BB), 512, 119808, stream>>>(xT16, K16, Vt16, betaA, Z);
    }

    bn_stats_kernel<<<BB * NN / 256, 256, 0, stream>>>(Z, bn);
    bn_apply_kernel<<<dim3(NN / 32, CC / 32, BB), 256, 0, stream>>>(Z, bn, gamma, beta, (float*)d_out);
}

// Round 20
// 583.198 us; speedup vs baseline: 1.0408x; 1.0271x over previous
//
#include <hip/hip_runtime.h>

#define BB 16
#define CC 256
#define NN 4096
#define MM 1024
#define EPSV 1e-5f
#define SCALE (1.0f/16.0f)   // 1/sqrt(C)

// ---- workspace layout (float offsets). ----
#define OFF_MU    0            // 4096  (musum; dead after score_fix -> u[257], b2, wob)
#define OFF_SCORE 4096         // 65536 (s2/score; dead after select -> beta)
#define OFF_IDX   69632        // 32768 ints (idx_s then idx_g)
#define OFF_U     102400       // 65536 (WoWv f32 scratch)
#define OFF_BVZ   299008       // 256
#define OFF_BZ    299264       // 256
#define OFF_W16   299520       // 4 bf16 weight mats = 131072 floats
#define OFF_XG    430592       // Xg bf16 [16*1024][256] = 2097152 floats
#define OFF_K16   2527744      // K'' bf16 = 2097152 floats
#define OFF_VT16  4624896      // Vt bf16 = 2097152 floats
#define OFF_Z     6722048      // 16777216 floats
#define OFF_BN    23499264     // 512

typedef __attribute__((ext_vector_type(8))) short s16x8;
typedef __attribute__((ext_vector_type(4))) float f32x4;

__device__ __forceinline__ unsigned short f2bf(float f) {
    unsigned int u = __float_as_uint(f);
    return (unsigned short)((u + 0x7FFFu + ((u >> 16) & 1u)) >> 16);
}
__device__ __forceinline__ float bf2f(unsigned short h) {
    return __uint_as_float(((unsigned int)h) << 16);
}

// zero musum+score (272 blocks) and bn (block 272) in one launch
__global__ __launch_bounds__(256) void zero_all_kernel(float* ws, float* bn) {
    if (blockIdx.x < 272) ws[blockIdx.x * 256 + threadIdx.x] = 0.f;
    else { bn[threadIdx.x] = 0.f; bn[threadIdx.x + CC] = 0.f; }
}

// x [B][C][N] f32 -> xT16 [B][N][C] bf16, fused with s2[b,n]=sum_c x^2 and
// musum[b,c]=sum_n x accumulation (score finalized by score_fix:
// score = s2 - (2/N)*xT·musum; +||mu||^2 is per-batch constant -> top-k invariant).
__global__ __launch_bounds__(256) void transpose_s2_kernel(const float* __restrict__ x,
                                                           unsigned short* __restrict__ xT,
                                                           float* __restrict__ score,
                                                           float* __restrict__ musum) {
    __shared__ float tile[32][33];
    int b = blockIdx.z, c0 = blockIdx.y * 32, n0 = blockIdx.x * 32, t = threadIdx.x;
    int nl = t & 31, cr = t >> 5;
#pragma unroll
    for (int q = 0; q < 4; ++q)
        tile[cr + q * 8][nl] = x[((size_t)b * CC + c0 + cr + q * 8) * NN + n0 + nl];
    __syncthreads();
    int nr = t >> 3, cq = t & 7;
    uint2 p;
    p.x = (unsigned int)f2bf(tile[cq * 4 + 0][nr]) | ((unsigned int)f2bf(tile[cq * 4 + 1][nr]) << 16);
    p.y = (unsigned int)f2bf(tile[cq * 4 + 2][nr]) | ((unsigned int)f2bf(tile[cq * 4 + 3][nr]) << 16);
    *(uint2*)&xT[((size_t)b * NN + n0 + nr) * CC + c0 + cq * 4] = p;
    int a = t & 31, seg = t >> 5;
    float ps2 = 0.f, pmu = 0.f;
#pragma unroll
    for (int q = 0; q < 4; ++q) {
        float v = tile[seg * 4 + q][a];
        ps2 += v * v;
        pmu += tile[a][seg * 4 + q];
    }
    __syncthreads();
    tile[a][seg] = ps2;
    tile[a][8 + seg] = pmu;
    __syncthreads();
    if (t < 32) {
        float s = 0.f;
#pragma unroll
        for (int j = 0; j < 8; ++j) s += tile[t][j];
        atomicAdd(&score[(size_t)b * NN + n0 + t], s);
    } else if (t < 64) {
        int r = t - 32;
        float s = 0.f;
#pragma unroll
        for (int j = 0; j < 8; ++j) s += tile[r][8 + j];
        atomicAdd(&musum[b * CC + c0 + r], s);
    }
}

// score[row] -= (2/N) * xT[row]·musum[b]   (one wave per row)
__global__ __launch_bounds__(256) void score_fix_kernel(const unsigned short* __restrict__ xT,
                                                        const float* __restrict__ musum,
                                                        float* __restrict__ score) {
    int row = blockIdx.x * 4 + (threadIdx.x >> 6);
    int l = threadIdx.x & 63;
    int b = row >> 12;
    uint2 p = *(const uint2*)&xT[(size_t)row * CC + l * 4];
    const float* ms = musum + b * CC + l * 4;
    float acc = bf2f((unsigned short)(p.x & 0xFFFF)) * ms[0]
              + bf2f((unsigned short)(p.x >> 16)) * ms[1]
              + bf2f((unsigned short)(p.y & 0xFFFF)) * ms[2]
              + bf2f((unsigned short)(p.y >> 16)) * ms[3];
    acc += __shfl_xor(acc, 1); acc += __shfl_xor(acc, 2); acc += __shfl_xor(acc, 4);
    acc += __shfl_xor(acc, 8); acc += __shfl_xor(acc, 16); acc += __shfl_xor(acc, 32);
    if (l == 0) score[row] -= acc * (2.0f / NN);
}

// radix-select: per batch, top-1024 set -> idx_s, bottom-1024 set -> idx_g (order arbitrary)
__global__ __launch_bounds__(1024) void select_kernel(const float* __restrict__ score,
                                                      int* __restrict__ idx_s, int* __restrict__ idx_g) {
    int b = blockIdx.x, t = threadIdx.x;
    __shared__ unsigned int keys[NN];
    __shared__ unsigned int hist[256];
    __shared__ unsigned int sbin, skrem;
    __shared__ int outcnt, eqcnt;
    __shared__ int eqidx[NN];
    for (int q = t; q < NN; q += 1024) keys[q] = __float_as_uint(score[(size_t)b * NN + q]);
    __syncthreads();
    for (int r = 0; r < 2; ++r) {
        unsigned int flip = r ? 0xFFFFFFFFu : 0u;
        unsigned int prefix = 0u, pmask = 0u;
        unsigned int k = MM;
        for (int pass = 0; pass < 4; ++pass) {
            int shift = 24 - 8 * pass;
            if (t < 256) hist[t] = 0u;
            __syncthreads();
            for (int q = t; q < NN; q += 1024) {
                unsigned int kv = keys[q] ^ flip;
                if ((kv & pmask) == prefix) atomicAdd(&hist[(kv >> shift) & 255u], 1u);
            }
            __syncthreads();
            for (int off = 1; off < 256; off <<= 1) {
                unsigned int v = 0u;
                if (t < 256) v = hist[t] + ((t + off < 256) ? hist[t + off] : 0u);
                __syncthreads();
                if (t < 256) hist[t] = v;
                __syncthreads();
            }
            if (t < 256) {
                unsigned int sj = hist[t], sj1 = (t < 255) ? hist[t + 1] : 0u;
                if (sj >= k && sj1 < k) { sbin = (unsigned int)t; skrem = k - sj1; }
            }
            __syncthreads();
            prefix |= sbin << shift;
            pmask |= 0xFFu << shift;
            k = skrem;
            __syncthreads();
        }
        unsigned int T = prefix;
        unsigned int krem = k;
        int* outp = r ? idx_g : idx_s;
        if (t == 0) { outcnt = 0; eqcnt = 0; }
        __syncthreads();
        for (int q = t; q < NN; q += 1024) {
            unsigned int kv = keys[q] ^ flip;
            if (kv > T) { int pp = atomicAdd(&outcnt, 1); outp[(size_t)b * MM + pp] = q; }
            else if (kv == T) { int pp = atomicAdd(&eqcnt, 1); eqidx[pp] = q; }
        }
        __syncthreads();
        int ne = eqcnt;
        for (int i = t; i < ne; i += 1024) {
            int me = eqidx[i];
            int rank = 0;
            for (int j = 0; j < ne; ++j) rank += (eqidx[j] < me) ? 1 : 0;
            if (rank < (int)krem) { int pp = atomicAdd(&outcnt, 1); outp[(size_t)b * MM + pp] = me; }
        }
        __syncthreads();
    }
}

__global__ __launch_bounds__(256) void bz_kernel(const float* __restrict__ Wf, const float* __restrict__ bf,
                                                 const float* __restrict__ bo_s, const float* __restrict__ bo_g,
                                                 float* __restrict__ bz) {
    int e = threadIdx.x;
    float acc = bf[e];
    for (int c = 0; c < CC; ++c)
        acc += Wf[e * 2 * CC + c] * bo_s[c] + Wf[e * 2 * CC + CC + c] * bo_g[c];
    bz[e] = acc;
}

// Wf12 -> bf16 directly (f32 intermediate + conv_bf16 launch eliminated)
__global__ __launch_bounds__(256) void wf12_kernel(const float* __restrict__ Wf,
                                                   unsigned short* __restrict__ Wf12_16) {
    int e = blockIdx.x, c = threadIdx.x;
    Wf12_16[e * CC + c] = f2bf(Wf[e * 2 * CC + c] + Wf[e * 2 * CC + CC + c]);
}

// ---- branch precompute, consolidated ----
__global__ __launch_bounds__(256) void prep1_kernel(
    const float* __restrict__ Wo, const float* __restrict__ Wv,
    const float* __restrict__ Wq, const float* __restrict__ Wk,
    const float* __restrict__ bq, const float* __restrict__ bk, const float* __restrict__ bv,
    float* __restrict__ WoWv, unsigned short* __restrict__ W2_16,
    float* __restrict__ wob, float* __restrict__ u, float* __restrict__ b2)
{
    int xr = blockIdx.x, y = blockIdx.y, t = threadIdx.x;
    if (y == 0) {
        __shared__ float arow[CC];
        arow[t] = Wo[xr * CC + t];
        __syncthreads();
        float acc = 0.f;
        for (int k = 0; k < CC; ++k) acc += arow[k] * Wv[k * CC + t];
        WoWv[xr * CC + t] = acc;
    } else if (y == 1) {
        __shared__ float aq[CC];
        aq[t] = Wq[t * CC + xr];
        __syncthreads();
        float acc = 0.f;
        for (int c = 0; c < CC; ++c) acc += aq[c] * Wk[c * CC + t];
        W2_16[xr * CC + t] = f2bf(acc);
    } else if (xr == 0) {
        float a1 = 0.f, a2 = 0.f, a3 = 0.f;
        for (int c = 0; c < CC; ++c) {
            a1 += Wo[t * CC + c] * bv[c];
            a2 += bq[c] * Wk[c * CC + t];
            a3 += Wq[c * CC + t] * bk[c];
        }
        wob[t] = a1; u[t] = a2; b2[t] = a3;
        if (t == 0) { float s = 0.f; for (int c = 0; c < CC; ++c) s += bq[c] * bk[c]; u[CC] = s; }
    }
}

__global__ __launch_bounds__(256) void prep2_kernel(
    const float* __restrict__ Wf, int aoff, const float* __restrict__ WoWv,
    const float* __restrict__ wob, unsigned short* __restrict__ Wvz16, float* __restrict__ bvz)
{
    int e = blockIdx.x, t = threadIdx.x;
    __shared__ float arow[CC];
    __shared__ float red[256];
    arow[t] = Wf[e * 2 * CC + aoff + t];
    __syncthreads();
    float acc = 0.f;
    for (int k = 0; k < CC; ++k) acc += arow[k] * WoWv[k * CC + t];
    Wvz16[e * CC + t] = f2bf(acc);
    red[t] = arow[t] * wob[t];
    __syncthreads();
    for (int w = 128; w > 0; w >>= 1) { if (t < w) red[t] += red[t + w]; __syncthreads(); }
    if (t == 0) bvz[e] = red[0];
}

// gather + beta fused: Xg[row] = xT[b][idx[row]]; beta[row] = Xg[row]·u + u[256]
__global__ __launch_bounds__(256) void gather_beta_kernel(const unsigned short* __restrict__ xT,
                                                          const int* __restrict__ idx,
                                                          const float* __restrict__ u,
                                                          unsigned short* __restrict__ Xg,
                                                          float* __restrict__ beta) {
    int row = blockIdx.x * 4 + (threadIdx.x >> 6);
    int l = threadIdx.x & 63;
    int b = row >> 10, m = row & (MM - 1);
    int src = idx[b * MM + m];
    uint2 p = *(const uint2*)&xT[((size_t)b * NN + src) * CC + l * 4];
    *(uint2*)&Xg[(size_t)row * CC + l * 4] = p;
    float acc = bf2f((unsigned short)(p.x & 0xFFFF)) * u[l * 4]
              + bf2f((unsigned short)(p.x >> 16)) * u[l * 4 + 1]
              + bf2f((unsigned short)(p.y & 0xFFFF)) * u[l * 4 + 2]
              + bf2f((unsigned short)(p.y >> 16)) * u[l * 4 + 3];
    acc += __shfl_xor(acc, 1); acc += __shfl_xor(acc, 2); acc += __shfl_xor(acc, 4);
    acc += __shfl_xor(acc, 8); acc += __shfl_xor(acc, 16); acc += __shfl_xor(acc, 32);
    if (l == 0) beta[row] = acc + u[CC];
}

// ---- generic bf16 MFMA GEMM: out[i][j] = sum_k A[i][k]*Bw[j][k] (+bias), 128x128 tile ----
template<int OMODE>
__global__ __launch_bounds__(256, 3) void gemm_bt(
    const unsigned short* __restrict__ A, size_t a_bs,
    const unsigned short* __restrict__ Bw, size_t b_bs,
    const float* __restrict__ bias,
    void* __restrict__ outp, size_t o_bs, int ldo)
{
    __shared__ __align__(16) unsigned short As[128 * 32];
    __shared__ __align__(16) unsigned short Bs[128 * 32];
    int z = blockIdx.z;
    const unsigned short* Ab = A + z * a_bs + (size_t)blockIdx.x * 128 * CC;
    const unsigned short* Bb = Bw + z * b_bs + (size_t)blockIdx.y * 128 * CC;
    int t = threadIdx.x, w = t >> 6, l = t & 63, g = l >> 4, c16 = l & 15;
    int wi = w >> 1, wj = w & 1;
    int srow = t >> 2, skq = (t & 3) * 8;

    f32x4 acc[4][4];
#pragma unroll
    for (int a = 0; a < 4; ++a)
#pragma unroll
        for (int bq = 0; bq < 4; ++bq) acc[a][bq] = (f32x4){0.f, 0.f, 0.f, 0.f};

    for (int ks = 0; ks < 8; ++ks) {
        int k0 = ks * 32;
        uint4 a0 = *(const uint4*)(Ab + (size_t)srow * CC + k0 + skq);
        uint4 a1 = *(const uint4*)(Ab + (size_t)(srow + 64) * CC + k0 + skq);
        uint4 b0 = *(const uint4*)(Bb + (size_t)srow * CC + k0 + skq);
        uint4 b1 = *(const uint4*)(Bb + (size_t)(srow + 64) * CC + k0 + skq);
        __syncthreads();
        *(uint4*)&As[srow * 32 + skq] = a0;
        *(uint4*)&As[(srow + 64) * 32 + skq] = a1;
        *(uint4*)&Bs[srow * 32 + skq] = b0;
        *(uint4*)&Bs[(srow + 64) * 32 + skq] = b1;
        __syncthreads();
        s16x8 af[4], bf4[4];
#pragma unroll
        for (int fi = 0; fi < 4; ++fi)
            af[fi] = *(const s16x8*)&As[(wi * 64 + fi * 16 + c16) * 32 + g * 8];
#pragma unroll
        for (int fj = 0; fj < 4; ++fj)
            bf4[fj] = *(const s16x8*)&Bs[(wj * 64 + fj * 16 + c16) * 32 + g * 8];
#pragma unroll
        for (int fi = 0; fi < 4; ++fi)
#pragma unroll
            for (int fj = 0; fj < 4; ++fj)
                acc[fi][fj] = __builtin_amdgcn_mfma_f32_16x16x32_bf16(af[fi], bf4[fj], acc[fi][fj], 0, 0, 0);
    }

    int i0 = blockIdx.x * 128 + wi * 64, j0 = blockIdx.y * 128 + wj * 64;
#pragma unroll
    for (int fi = 0; fi < 4; ++fi) {
#pragma unroll
        for (int fj = 0; fj < 4; ++fj) {
            int colg = j0 + fj * 16 + c16;
#pragma unroll
            for (int r = 0; r < 4; ++r) {
                int rowg = i0 + fi * 16 + g * 4 + r;
                float v = acc[fi][fj][r] + (OMODE == 2 ? bias[rowg] : bias[colg]);
                if (OMODE == 0)
                    ((float*)outp)[z * o_bs + (size_t)rowg * ldo + colg] = v;
                else
                    ((unsigned short*)outp)[z * o_bs + (size_t)rowg * ldo + colg] = f2bf(v);
            }
        }
    }
}

// ---- fused flash-style attention: Z[z][n][e] += (exp((xT·K''^T + beta)/16)·V) / rsum[n] ----
// EXACT round-13/19 shape (112us/dispatch, no spill, VGPR=104). Do not touch.
__global__ __attribute__((amdgpu_flat_work_group_size(512, 512)))
__attribute__((amdgpu_waves_per_eu(2, 2)))
void fused_attn(
    const unsigned short* __restrict__ Q,    // xT [B][N][C] bf16
    const unsigned short* __restrict__ K,    // K'' [B][M][C] bf16 (b2 included)
    const unsigned short* __restrict__ Vt,   // [B][C][M] bf16 (bias included)
    const float* __restrict__ beta,          // [B][M]
    float* __restrict__ Z)                   // [B][N][C] +=
{
    extern __shared__ __align__(16) unsigned char smem[];
    // [K0 16K][K1 16K][V0 16K][V1 16K][V2 16K][P0 16K][P1 16K][rsl 1K][beta 4K]
    float* rsl = (float*)(smem + 114688);
    float* bs  = (float*)(smem + 115712);

    int z = blockIdx.z;
    int n0 = blockIdx.x * 128;
    int t = threadIdx.x, w = t >> 6, l = t & 63, g = l >> 4, c16 = l & 15;
    int wn = w >> 1, wc = w & 1;   // wave grid: 4 n-rows x 2 m/e-cols

    const unsigned short* Qb = Q + ((size_t)z * NN + n0) * CC;
    const char* Kzb = (const char*)(K + (size_t)z * MM * CC);
    const char* Vzb = (const char*)(Vt + (size_t)z * CC * MM);

    // beta table -> LDS (visible after prologue __syncthreads)
    bs[t] = beta[(size_t)z * MM + t];
    bs[t + 512] = beta[(size_t)z * MM + t + 512];

    // Q fragments: rows wn*32 + fi*16 + c16, k = ks*32 + g*8  (64 VGPR)
    s16x8 q[2][8];
#pragma unroll
    for (int fi = 0; fi < 2; ++fi)
#pragma unroll
        for (int ks = 0; ks < 8; ++ks)
            q[fi][ks] = *(const s16x8*)&Qb[(size_t)(wn * 32 + fi * 16 + c16) * CC + ks * 32 + g * 8];

    f32x4 o[2][8];
#pragma unroll
    for (int fi = 0; fi < 2; ++fi)
#pragma unroll
        for (int fj = 0; fj < 8; ++fj) o[fi][fj] = (f32x4){0.f, 0.f, 0.f, 0.f};
    float rs[2][4];
#pragma unroll
    for (int fi = 0; fi < 2; ++fi)
#pragma unroll
        for (int r = 0; r < 4; ++r) rs[fi][r] = 0.f;

    // gll staging (LDS linear, global source pre-XOR'd). K tile 16KB: 32 rows x 512B.
    auto issueK = [&](int buf, int m0) {
#pragma unroll
        for (int j = 0; j < 2; ++j) {
            int cid = w * 2 + j;
            int row = cid * 2 + (l >> 5);
            int srcoff = ((l & 31) * 16) ^ ((row & 7) << 4);
            const char* gp = Kzb + (size_t)(m0 + row) * 512 + srcoff;
            __builtin_amdgcn_global_load_lds(
                (const __attribute__((address_space(1))) void*)gp,
                (__attribute__((address_space(3))) void*)(smem + buf * 16384 + cid * 1024),
                16, 0, 0);
        }
    };
    // V tile 16KB: 256 rows x 64B; swizzle ^(((row>>1)&3)<<4) — bits 4-5 only (in-row)
    auto issueV = [&](int slot, int m0) {
#pragma unroll
        for (int j = 0; j < 2; ++j) {
            int cid = w * 2 + j;
            int row = cid * 16 + (l >> 2);
            int srcoff = ((l & 3) * 16) ^ (((row >> 1) & 3) << 4);
            const char* gp = Vzb + (size_t)row * 2048 + (size_t)m0 * 2 + srcoff;
            __builtin_amdgcn_global_load_lds(
                (const __attribute__((address_space(1))) void*)gp,
                (__attribute__((address_space(3))) void*)(smem + 32768 + slot * 16384 + cid * 1024),
                16, 0, 0);
        }
    };

    // QK(t)+exp -> P[par]. sacc: n-row = wn*32+fi*16+g*4+r, m = m0 + wc*16 + c16.
    auto qk_exp = [&](int buf, int par, int m0) {
        const unsigned char* Ks = smem + buf * 16384;
        unsigned char* Ps = smem + 81920 + par * 16384;
        f32x4 sacc[2];
#pragma unroll
        for (int fi = 0; fi < 2; ++fi) sacc[fi] = (f32x4){0.f, 0.f, 0.f, 0.f};
        int mr = wc * 16 + c16;
        __builtin_amdgcn_s_setprio(1);
#pragma unroll
        for (int ks = 0; ks < 8; ++ks) {
            s16x8 kf = *(const s16x8*)(Ks + ((mr * 512 + ks * 64 + g * 16) ^ ((mr & 7) << 4)));
#pragma unroll
            for (int fi = 0; fi < 2; ++fi)
                sacc[fi] = __builtin_amdgcn_mfma_f32_16x16x32_bf16(q[fi][ks], kf, sacc[fi], 0, 0, 0);
        }
        __builtin_amdgcn_s_setprio(0);
        float bet = bs[m0 + wc * 16 + c16];
#pragma unroll
        for (int fi = 0; fi < 2; ++fi)
#pragma unroll
            for (int r = 0; r < 4; ++r) {
                float e = __expf((sacc[fi][r] + bet) * SCALE);
                unsigned short h = f2bf(e);
                int nr = wn * 32 + fi * 16 + g * 4 + r;
                *(unsigned short*)(Ps + ((nr * 128 + (wc * 16 + c16) * 2) ^ ((nr & 7) << 4))) = h;
                rs[fi][r] += bf2f(h);
            }
    };
    // PV(t): O += P[par] · V[slot]
    auto pv = [&](int slot, int par) {
        const unsigned char* Vs = smem + 32768 + slot * 16384;
        const unsigned char* Ps = smem + 81920 + par * 16384;
        s16x8 pa[2];
#pragma unroll
        for (int fi = 0; fi < 2; ++fi) {
            int nr = wn * 32 + fi * 16 + c16;
            pa[fi] = *(const s16x8*)(Ps + ((nr * 128 + g * 16) ^ ((nr & 7) << 4)));
        }
        __builtin_amdgcn_s_setprio(1);
#pragma unroll
        for (int fj = 0; fj < 8; ++fj) {
            int er = wc * 128 + fj * 16 + c16;
            s16x8 vb = *(const s16x8*)(Vs + ((er * 64 + g * 16) ^ (((er >> 1) & 3) << 4)));
#pragma unroll
            for (int fi = 0; fi < 2; ++fi)
                o[fi][fj] = __builtin_amdgcn_mfma_f32_16x16x32_bf16(pa[fi], vb, o[fi][fj], 0, 0, 0);
        }
        __builtin_amdgcn_s_setprio(0);
    };

    // prologue: stage tiles 0,1; compute QK(0)->P[0]
    issueK(0, 0); issueV(0, 0);
    issueK(1, 32); issueV(1, 32);
    __syncthreads();
    qk_exp(0, 0, 0);

    for (int mt = 0; mt < 32; ++mt) {
        __syncthreads();   // publishes P[mt&1]; drains gll issued last interval
        if (mt < 30) {
            issueK(mt & 1, (mt + 2) * 32);
            issueV((mt + 2) % 3, (mt + 2) * 32);
        }
        __builtin_amdgcn_sched_barrier(0);
        if (mt < 31) qk_exp((mt + 1) & 1, (mt + 1) & 1, (mt + 1) * 32);
        pv(mt % 3, mt & 1);
    }

    // cross-lane + cross-wave rsum
#pragma unroll
    for (int fi = 0; fi < 2; ++fi)
#pragma unroll
        for (int r = 0; r < 4; ++r) {
            float v = rs[fi][r];
            v += __shfl_xor(v, 1); v += __shfl_xor(v, 2);
            v += __shfl_xor(v, 4); v += __shfl_xor(v, 8);
            if (c16 == 0) rsl[wc * 128 + wn * 32 + fi * 16 + g * 4 + r] = v;
        }
    __syncthreads();
    float* Zb = Z + ((size_t)z * NN + n0) * CC;
#pragma unroll
    for (int fi = 0; fi < 2; ++fi)
#pragma unroll
        for (int r = 0; r < 4; ++r) {
            int nr = wn * 32 + fi * 16 + g * 4 + r;
            float inv = 1.0f / (rsl[nr] + rsl[128 + nr]);
#pragma unroll
            for (int fj = 0; fj < 8; ++fj) {
                int e = wc * 128 + fj * 16 + c16;
                Zb[(size_t)nr * CC + e] += o[fi][fj][r] * inv;
            }
        }
}

// BN stats: per-channel sum and sumsq over B*N rows of Z [B*N][C]
__global__ __launch_bounds__(256) void bn_stats_kernel(const float* __restrict__ Z, float* __restrict__ bn) {
    int blk = blockIdx.x, e = threadIdx.x;
    const float* p = Z + (size_t)blk * 256 * CC + e;
    float s1 = 0.f, s2 = 0.f;
    for (int r = 0; r < 256; ++r) { float v = p[(size_t)r * CC]; s1 += v; s2 += v * v; }
    atomicAdd(&bn[e], s1);
    atomicAdd(&bn[CC + e], s2);
}

// normalize + relu + transpose [B][N][C] -> [B][C][N]
__global__ __launch_bounds__(256) void bn_apply_kernel(const float* __restrict__ Z, const float* __restrict__ bn,
                                                       const float* __restrict__ gamma, const float* __restrict__ beta,
                                                       float* __restrict__ out) {
    int b = blockIdx.z, e0 = blockIdx.y * 32, n0 = blockIdx.x * 32, t = threadIdx.x;
    __shared__ float tile[32][33];
    int c = t & 31, r0 = (t >> 5) * 4;
#pragma unroll
    for (int q = 0; q < 4; ++q)
        tile[r0 + q][c] = Z[((size_t)b * NN + n0 + r0 + q) * CC + e0 + c];
    __syncthreads();
    int n = t & 31, er0 = (t >> 5) * 4;
    const float invcnt = 1.0f / (BB * NN);
#pragma unroll
    for (int q = 0; q < 4; ++q) {
        int e = e0 + er0 + q;
        float mean = bn[e] * invcnt;
        float var = bn[CC + e] * invcnt - mean * mean;
        float rsq = rsqrtf(var + EPSV);
        float v = (tile[n][er0 + q] - mean) * rsq * gamma[e] + beta[e];
        out[((size_t)b * CC + e) * NN + n0 + n] = fmaxf(v, 0.f);
    }
}

extern "C" void kernel_launch(void* const* d_in, const int* in_sizes, int n_in,
                              void* d_out, int out_size, void* d_ws, size_t ws_size,
                              hipStream_t stream) {
    const float* x    = (const float*)d_in[0];
    const float* Wq_s = (const float*)d_in[2];  const float* bq_s = (const float*)d_in[3];
    const float* Wk_s = (const float*)d_in[4];  const float* bk_s = (const float*)d_in[5];
    const float* Wv_s = (const float*)d_in[6];  const float* bv_s = (const float*)d_in[7];
    const float* Wo_s = (const float*)d_in[8];  const float* bo_s = (const float*)d_in[9];
    const float* Wq_g = (const float*)d_in[10]; const float* bq_g = (const float*)d_in[11];
    const float* Wk_g = (const float*)d_in[12]; const float* bk_g = (const float*)d_in[13];
    const float* Wv_g = (const float*)d_in[14]; const float* bv_g = (const float*)d_in[15];
    const float* Wo_g = (const float*)d_in[16]; const float* bo_g = (const float*)d_in[17];
    const float* Wf   = (const float*)d_in[18]; const float* bf   = (const float*)d_in[19];
    const float* gamma = (const float*)d_in[20]; const float* beta = (const float*)d_in[21];

    float* ws    = (float*)d_ws;
    float* musum = ws + OFF_MU;
    float* score = ws + OFF_SCORE;
    int*   idx_s = (int*)(ws + OFF_IDX);
    int*   idx_g = idx_s + BB * MM;
    float* WoWv  = ws + OFF_U;
    float* bvz   = ws + OFF_BVZ;
    float* bz    = ws + OFF_BZ;
    float* uvec  = ws + OFF_MU;            // musum dead after score_fix; 257 floats
    float* b2    = ws + OFF_MU + 512;
    float* wob   = ws + OFF_MU + 1024;
    float* betaA = ws + OFF_SCORE;         // score dead after select
    unsigned short* Wf12_16 = (unsigned short*)(ws + OFF_W16);
    unsigned short* W2_16   = Wf12_16 + 65536;
    unsigned short* Wvz16   = W2_16 + 65536;
    unsigned short* Xg16 = (unsigned short*)(ws + OFF_XG);
    unsigned short* K16  = (unsigned short*)(ws + OFF_K16);
    unsigned short* Vt16 = (unsigned short*)(ws + OFF_VT16);
    float* Z     = ws + OFF_Z;
    float* bn    = ws + OFF_BN;
    // d_out doubles as scratch: second half holds xT16 (dead before bn_apply writes)
    unsigned short* xT16 = (unsigned short*)d_out + (size_t)BB * NN * CC;

    // zero musum+score (ws[0..69632)) and bn, one launch
    zero_all_kernel<<<273, 256, 0, stream>>>(ws, bn);
    transpose_s2_kernel<<<dim3(NN / 32, CC / 32, BB), 256, 0, stream>>>(x, xT16, score, musum);
    score_fix_kernel<<<BB * NN / 4, 256, 0, stream>>>(xT16, musum, score);
    select_kernel<<<BB, 1024, 0, stream>>>(score, idx_s, idx_g);
    wf12_kernel<<<CC, 256, 0, stream>>>(Wf, Wf12_16);
    bz_kernel<<<1, 256, 0, stream>>>(Wf, bf, bo_s, bo_g, bz);
    // Z = xT @ Wf12^T + bz  (residual x through both conv halves)
    gemm_bt<0><<<dim3(512, 2, 1), 256, 0, stream>>>(xT16, 0, Wf12_16, 0, bz, Z, 0, CC);

    for (int br = 0; br < 2; ++br) {
        const float* Wo = br ? Wo_g : Wo_s;
        const float* Wv = br ? Wv_g : Wv_s;  const float* bv = br ? bv_g : bv_s;
        const float* Wk = br ? Wk_g : Wk_s;  const float* bk = br ? bk_g : bk_s;
        const float* Wq = br ? Wq_g : Wq_s;  const float* bq = br ? bq_g : bq_s;
        int* idx = br ? idx_g : idx_s;
        int aoff = br ? CC : 0;
        prep1_kernel<<<dim3(CC, 3), 256, 0, stream>>>(Wo, Wv, Wq, Wk, bq, bk, bv,
                                                      WoWv, W2_16, wob, uvec, b2);
        prep2_kernel<<<CC, 256, 0, stream>>>(Wf, aoff, WoWv, wob, Wvz16, bvz);
        // gather + beta fused (u from prep1 is ready)
        gather_beta_kernel<<<BB * MM / 4, 256, 0, stream>>>(xT16, idx, uvec, Xg16, betaA);
        gemm_bt<1><<<dim3(BB * MM / 128, 2, 1), 256, 0, stream>>>(Xg16, 0, W2_16, 0, b2, K16, 0, CC);
        gemm_bt<2><<<dim3(2, 8, BB), 256, 0, stream>>>(Wvz16, 0, Xg16, (size_t)MM * CC, bvz,
                                                       Vt16, (size_t)CC * MM, MM);

        // fused flash attention: Z += softmax((xT·K''^T + beta)/16)·V
        fused_attn<<<dim3(NN / 128, 1, BB), 512, 119808, stream>>>(xT16, K16, Vt16, betaA, Z);
    }

    bn_stats_kernel<<<BB * NN / 256, 256, 0, stream>>>(Z, bn);
    bn_apply_kernel<<<dim3(NN / 32, CC / 32, BB), 256, 0, stream>>>(Z, bn, gamma, beta, (float*)d_out);
}

// Round 21
// 552.646 us; speedup vs baseline: 1.0984x; 1.0553x over previous
//
#include <hip/hip_runtime.h>

#define BB 16
#define CC 256
#define NN 4096
#define MM 1024
#define EPSV 1e-5f
#define SCALE (1.0f/16.0f)   // 1/sqrt(C)

// ---- workspace layout (float offsets). ----
#define OFF_MU    0            // 4096: musum; after select -> per-branch u/b2/wob (stride 2048)
#define OFF_SCORE 4096         // 65536: s2/score; after select -> beta2 [2][B*M]
#define OFF_IDX   69632        // 32768 ints (idx_s then idx_g)
#define OFF_U     102400       // 131072: WoWv2 [2][65536] f32
#define OFF_WVZ2  233472       // 65536 f32 = Wvz2 [2][65536] bf16
#define OFF_BVZ   299008       // 512: bvz2 [2][256]
#define OFF_W16   299520       // 131072 f32 = 4 bf16 mats: Wf12, W2s, W2g, (last 32768 f32: bz)
#define OFF_K16   2527744      // 4194304 f32 = K2 [2][B*M*C] bf16
#define OFF_Z     6722048      // 16777216 floats
#define OFF_BN    23499264     // 512

typedef __attribute__((ext_vector_type(8))) short s16x8;
typedef __attribute__((ext_vector_type(4))) float f32x4;

__device__ __forceinline__ unsigned short f2bf(float f) {
    unsigned int u = __float_as_uint(f);
    return (unsigned short)((u + 0x7FFFu + ((u >> 16) & 1u)) >> 16);
}
__device__ __forceinline__ float bf2f(unsigned short h) {
    return __uint_as_float(((unsigned int)h) << 16);
}

// zero musum+score (272 blocks) and bn (block 272) in one launch
__global__ __launch_bounds__(256) void zero_all_kernel(float* ws, float* bn) {
    if (blockIdx.x < 272) ws[blockIdx.x * 256 + threadIdx.x] = 0.f;
    else { bn[threadIdx.x] = 0.f; bn[threadIdx.x + CC] = 0.f; }
}

// x [B][C][N] f32 -> xT16 [B][N][C] bf16, fused with s2[b,n]=sum_c x^2 and
// musum[b,c]=sum_n x (score = s2 - (2/N)*xT·musum via score_fix; +||mu||^2 const).
__global__ __launch_bounds__(256) void transpose_s2_kernel(const float* __restrict__ x,
                                                           unsigned short* __restrict__ xT,
                                                           float* __restrict__ score,
                                                           float* __restrict__ musum) {
    __shared__ float tile[32][33];
    int b = blockIdx.z, c0 = blockIdx.y * 32, n0 = blockIdx.x * 32, t = threadIdx.x;
    int nl = t & 31, cr = t >> 5;
#pragma unroll
    for (int q = 0; q < 4; ++q)
        tile[cr + q * 8][nl] = x[((size_t)b * CC + c0 + cr + q * 8) * NN + n0 + nl];
    __syncthreads();
    int nr = t >> 3, cq = t & 7;
    uint2 p;
    p.x = (unsigned int)f2bf(tile[cq * 4 + 0][nr]) | ((unsigned int)f2bf(tile[cq * 4 + 1][nr]) << 16);
    p.y = (unsigned int)f2bf(tile[cq * 4 + 2][nr]) | ((unsigned int)f2bf(tile[cq * 4 + 3][nr]) << 16);
    *(uint2*)&xT[((size_t)b * NN + n0 + nr) * CC + c0 + cq * 4] = p;
    int a = t & 31, seg = t >> 5;
    float ps2 = 0.f, pmu = 0.f;
#pragma unroll
    for (int q = 0; q < 4; ++q) {
        float v = tile[seg * 4 + q][a];
        ps2 += v * v;
        pmu += tile[a][seg * 4 + q];
    }
    __syncthreads();
    tile[a][seg] = ps2;
    tile[a][8 + seg] = pmu;
    __syncthreads();
    if (t < 32) {
        float s = 0.f;
#pragma unroll
        for (int j = 0; j < 8; ++j) s += tile[t][j];
        atomicAdd(&score[(size_t)b * NN + n0 + t], s);
    } else if (t < 64) {
        int r = t - 32;
        float s = 0.f;
#pragma unroll
        for (int j = 0; j < 8; ++j) s += tile[r][8 + j];
        atomicAdd(&musum[b * CC + c0 + r], s);
    }
}

// score[row] -= (2/N) * xT[row]·musum[b]   (one wave per row)
__global__ __launch_bounds__(256) void score_fix_kernel(const unsigned short* __restrict__ xT,
                                                        const float* __restrict__ musum,
                                                        float* __restrict__ score) {
    int row = blockIdx.x * 4 + (threadIdx.x >> 6);
    int l = threadIdx.x & 63;
    int b = row >> 12;
    uint2 p = *(const uint2*)&xT[(size_t)row * CC + l * 4];
    const float* ms = musum + b * CC + l * 4;
    float acc = bf2f((unsigned short)(p.x & 0xFFFF)) * ms[0]
              + bf2f((unsigned short)(p.x >> 16)) * ms[1]
              + bf2f((unsigned short)(p.y & 0xFFFF)) * ms[2]
              + bf2f((unsigned short)(p.y >> 16)) * ms[3];
    acc += __shfl_xor(acc, 1); acc += __shfl_xor(acc, 2); acc += __shfl_xor(acc, 4);
    acc += __shfl_xor(acc, 8); acc += __shfl_xor(acc, 16); acc += __shfl_xor(acc, 32);
    if (l == 0) score[row] -= acc * (2.0f / NN);
}

// radix-select: per batch, top-1024 set -> idx_s, bottom-1024 set -> idx_g (order arbitrary)
__global__ __launch_bounds__(1024) void select_kernel(const float* __restrict__ score,
                                                      int* __restrict__ idx_s, int* __restrict__ idx_g) {
    int b = blockIdx.x, t = threadIdx.x;
    __shared__ unsigned int keys[NN];
    __shared__ unsigned int hist[256];
    __shared__ unsigned int sbin, skrem;
    __shared__ int outcnt, eqcnt;
    __shared__ int eqidx[NN];
    for (int q = t; q < NN; q += 1024) keys[q] = __float_as_uint(score[(size_t)b * NN + q]);
    __syncthreads();
    for (int r = 0; r < 2; ++r) {
        unsigned int flip = r ? 0xFFFFFFFFu : 0u;
        unsigned int prefix = 0u, pmask = 0u;
        unsigned int k = MM;
        for (int pass = 0; pass < 4; ++pass) {
            int shift = 24 - 8 * pass;
            if (t < 256) hist[t] = 0u;
            __syncthreads();
            for (int q = t; q < NN; q += 1024) {
                unsigned int kv = keys[q] ^ flip;
                if ((kv & pmask) == prefix) atomicAdd(&hist[(kv >> shift) & 255u], 1u);
            }
            __syncthreads();
            for (int off = 1; off < 256; off <<= 1) {
                unsigned int v = 0u;
                if (t < 256) v = hist[t] + ((t + off < 256) ? hist[t + off] : 0u);
                __syncthreads();
                if (t < 256) hist[t] = v;
                __syncthreads();
            }
            if (t < 256) {
                unsigned int sj = hist[t], sj1 = (t < 255) ? hist[t + 1] : 0u;
                if (sj >= k && sj1 < k) { sbin = (unsigned int)t; skrem = k - sj1; }
            }
            __syncthreads();
            prefix |= sbin << shift;
            pmask |= 0xFFu << shift;
            k = skrem;
            __syncthreads();
        }
        unsigned int T = prefix;
        unsigned int krem = k;
        int* outp = r ? idx_g : idx_s;
        if (t == 0) { outcnt = 0; eqcnt = 0; }
        __syncthreads();
        for (int q = t; q < NN; q += 1024) {
            unsigned int kv = keys[q] ^ flip;
            if (kv > T) { int pp = atomicAdd(&outcnt, 1); outp[(size_t)b * MM + pp] = q; }
            else if (kv == T) { int pp = atomicAdd(&eqcnt, 1); eqidx[pp] = q; }
        }
        __syncthreads();
        int ne = eqcnt;
        for (int i = t; i < ne; i += 1024) {
            int me = eqidx[i];
            int rank = 0;
            for (int j = 0; j < ne; ++j) rank += (eqidx[j] < me) ? 1 : 0;
            if (rank < (int)krem) { int pp = atomicAdd(&outcnt, 1); outp[(size_t)b * MM + pp] = me; }
        }
        __syncthreads();
    }
}

// wf12 (blocks 0..255) + bz (block 256), one launch
__global__ __launch_bounds__(256) void wf12bz_kernel(const float* __restrict__ Wf,
                                                     const float* __restrict__ bf,
                                                     const float* __restrict__ bo_s,
                                                     const float* __restrict__ bo_g,
                                                     unsigned short* __restrict__ Wf12_16,
                                                     float* __restrict__ bz) {
    int e = blockIdx.x, t = threadIdx.x;
    if (e < 256) {
        Wf12_16[e * CC + t] = f2bf(Wf[e * 2 * CC + t] + Wf[e * 2 * CC + CC + t]);
    } else {
        float acc = bf[t];
        for (int c = 0; c < CC; ++c)
            acc += Wf[t * 2 * CC + c] * bo_s[c] + Wf[t * 2 * CC + CC + c] * bo_g[c];
        bz[t] = acc;
    }
}

// ---- branch precompute, batched over branch (blockIdx.z) ----
__global__ __launch_bounds__(256) void prep1_kernel(
    const float* __restrict__ Wo0, const float* __restrict__ Wv0,
    const float* __restrict__ Wq0, const float* __restrict__ Wk0,
    const float* __restrict__ bq0, const float* __restrict__ bk0, const float* __restrict__ bv0,
    const float* __restrict__ Wo1, const float* __restrict__ Wv1,
    const float* __restrict__ Wq1, const float* __restrict__ Wk1,
    const float* __restrict__ bq1, const float* __restrict__ bk1, const float* __restrict__ bv1,
    float* __restrict__ WoWv2, unsigned short* __restrict__ W2pair,
    float* __restrict__ ubw)   // per branch: u at br*2048, b2 at br*2048+512, wob at br*2048+1024
{
    int xr = blockIdx.x, y = blockIdx.y, t = threadIdx.x;
    int br = blockIdx.z;
    const float* Wo = br ? Wo1 : Wo0;  const float* Wv = br ? Wv1 : Wv0;
    const float* Wq = br ? Wq1 : Wq0;  const float* Wk = br ? Wk1 : Wk0;
    const float* bq = br ? bq1 : bq0;  const float* bk = br ? bk1 : bk0;
    const float* bv = br ? bv1 : bv0;
    if (y == 0) {
        __shared__ float arow[CC];
        arow[t] = Wo[xr * CC + t];
        __syncthreads();
        float acc = 0.f;
        for (int k = 0; k < CC; ++k) acc += arow[k] * Wv[k * CC + t];
        WoWv2[br * 65536 + xr * CC + t] = acc;
    } else if (y == 1) {
        __shared__ float aq[CC];
        aq[t] = Wq[t * CC + xr];
        __syncthreads();
        float acc = 0.f;
        for (int c = 0; c < CC; ++c) acc += aq[c] * Wk[c * CC + t];
        W2pair[br * 65536 + xr * CC + t] = f2bf(acc);
    } else if (xr == 0) {
        float a1 = 0.f, a2 = 0.f, a3 = 0.f;
        for (int c = 0; c < CC; ++c) {
            a1 += Wo[t * CC + c] * bv[c];
            a2 += bq[c] * Wk[c * CC + t];
            a3 += Wq[c * CC + t] * bk[c];
        }
        float* base = ubw + br * 2048;
        base[1024 + t] = a1;   // wob
        base[t] = a2;          // u
        base[512 + t] = a3;    // b2
        if (t == 0) { float s = 0.f; for (int c = 0; c < CC; ++c) s += bq[c] * bk[c]; base[CC] = s; }
    }
}

__global__ __launch_bounds__(256) void prep2_kernel(
    const float* __restrict__ Wf, const float* __restrict__ WoWv2,
    const float* __restrict__ ubw, unsigned short* __restrict__ Wvz2, float* __restrict__ bvz2)
{
    int e = blockIdx.x, br = blockIdx.y, t = threadIdx.x;
    int aoff = br * CC;
    __shared__ float arow[CC];
    __shared__ float red[256];
    arow[t] = Wf[e * 2 * CC + aoff + t];
    __syncthreads();
    float acc = 0.f;
    const float* WoWv = WoWv2 + br * 65536;
    for (int k = 0; k < CC; ++k) acc += arow[k] * WoWv[k * CC + t];
    Wvz2[br * 65536 + e * CC + t] = f2bf(acc);
    red[t] = arow[t] * ubw[br * 2048 + 1024 + t];
    __syncthreads();
    for (int w = 128; w > 0; w >>= 1) { if (t < w) red[t] += red[t + w]; __syncthreads(); }
    if (t == 0) bvz2[br * 256 + e] = red[0];
}

// gather + beta, batched over branch: Xg2[br][row] = xT[b][idx_br[row]];
// beta2[br][row] = Xg·u_br + const
__global__ __launch_bounds__(256) void gather_beta_kernel(const unsigned short* __restrict__ xT,
                                                          const int* __restrict__ idx_s,
                                                          const int* __restrict__ idx_g,
                                                          const float* __restrict__ ubw,
                                                          unsigned short* __restrict__ Xg2,
                                                          float* __restrict__ beta2) {
    int row = blockIdx.x * 4 + (threadIdx.x >> 6);
    int l = threadIdx.x & 63;
    int br = blockIdx.y;
    int b = row >> 10, m = row & (MM - 1);
    const int* idx = br ? idx_g : idx_s;
    const float* u = ubw + br * 2048;
    int src = idx[b * MM + m];
    uint2 p = *(const uint2*)&xT[((size_t)b * NN + src) * CC + l * 4];
    *(uint2*)&Xg2[(size_t)br * BB * MM * CC + (size_t)row * CC + l * 4] = p;
    float acc = bf2f((unsigned short)(p.x & 0xFFFF)) * u[l * 4]
              + bf2f((unsigned short)(p.x >> 16)) * u[l * 4 + 1]
              + bf2f((unsigned short)(p.y & 0xFFFF)) * u[l * 4 + 2]
              + bf2f((unsigned short)(p.y >> 16)) * u[l * 4 + 3];
    acc += __shfl_xor(acc, 1); acc += __shfl_xor(acc, 2); acc += __shfl_xor(acc, 4);
    acc += __shfl_xor(acc, 8); acc += __shfl_xor(acc, 16); acc += __shfl_xor(acc, 32);
    if (l == 0) beta2[br * BB * MM + row] = acc + u[CC];
}

// ---- generic bf16 MFMA GEMM: out[i][j] = sum_k A[i][k]*Bw[j][k] (+bias), 128x128 tile ----
// A and bias are indexed by (z >> az_shift); B and out by z.
template<int OMODE>
__global__ __launch_bounds__(256, 3) void gemm_bt(
    const unsigned short* __restrict__ A, size_t a_bs,
    const unsigned short* __restrict__ Bw, size_t b_bs,
    const float* __restrict__ bias, size_t bias_bs, int az_shift,
    void* __restrict__ outp, size_t o_bs, int ldo)
{
    __shared__ __align__(16) unsigned short As[128 * 32];
    __shared__ __align__(16) unsigned short Bs[128 * 32];
    int z = blockIdx.z;
    int az = z >> az_shift;
    const unsigned short* Ab = A + (size_t)az * a_bs + (size_t)blockIdx.x * 128 * CC;
    const unsigned short* Bb = Bw + (size_t)z * b_bs + (size_t)blockIdx.y * 128 * CC;
    const float* biasb = bias + (size_t)az * bias_bs;
    int t = threadIdx.x, w = t >> 6, l = t & 63, g = l >> 4, c16 = l & 15;
    int wi = w >> 1, wj = w & 1;
    int srow = t >> 2, skq = (t & 3) * 8;

    f32x4 acc[4][4];
#pragma unroll
    for (int a = 0; a < 4; ++a)
#pragma unroll
        for (int bq = 0; bq < 4; ++bq) acc[a][bq] = (f32x4){0.f, 0.f, 0.f, 0.f};

    for (int ks = 0; ks < 8; ++ks) {
        int k0 = ks * 32;
        uint4 a0 = *(const uint4*)(Ab + (size_t)srow * CC + k0 + skq);
        uint4 a1 = *(const uint4*)(Ab + (size_t)(srow + 64) * CC + k0 + skq);
        uint4 b0 = *(const uint4*)(Bb + (size_t)srow * CC + k0 + skq);
        uint4 b1 = *(const uint4*)(Bb + (size_t)(srow + 64) * CC + k0 + skq);
        __syncthreads();
        *(uint4*)&As[srow * 32 + skq] = a0;
        *(uint4*)&As[(srow + 64) * 32 + skq] = a1;
        *(uint4*)&Bs[srow * 32 + skq] = b0;
        *(uint4*)&Bs[(srow + 64) * 32 + skq] = b1;
        __syncthreads();
        s16x8 af[4], bf4[4];
#pragma unroll
        for (int fi = 0; fi < 4; ++fi)
            af[fi] = *(const s16x8*)&As[(wi * 64 + fi * 16 + c16) * 32 + g * 8];
#pragma unroll
        for (int fj = 0; fj < 4; ++fj)
            bf4[fj] = *(const s16x8*)&Bs[(wj * 64 + fj * 16 + c16) * 32 + g * 8];
#pragma unroll
        for (int fi = 0; fi < 4; ++fi)
#pragma unroll
            for (int fj = 0; fj < 4; ++fj)
                acc[fi][fj] = __builtin_amdgcn_mfma_f32_16x16x32_bf16(af[fi], bf4[fj], acc[fi][fj], 0, 0, 0);
    }

    int i0 = blockIdx.x * 128 + wi * 64, j0 = blockIdx.y * 128 + wj * 64;
#pragma unroll
    for (int fi = 0; fi < 4; ++fi) {
#pragma unroll
        for (int fj = 0; fj < 4; ++fj) {
            int colg = j0 + fj * 16 + c16;
#pragma unroll
            for (int r = 0; r < 4; ++r) {
                int rowg = i0 + fi * 16 + g * 4 + r;
                float v = acc[fi][fj][r] + (OMODE == 2 ? biasb[rowg] : biasb[colg]);
                if (OMODE == 0)
                    ((float*)outp)[(size_t)z * o_bs + (size_t)rowg * ldo + colg] = v;
                else
                    ((unsigned short*)outp)[(size_t)z * o_bs + (size_t)rowg * ldo + colg] = f2bf(v);
            }
        }
    }
}

// ---- fused flash-style attention: Z[z][n][e] += (exp((xT·K''^T + beta)/16)·V) / rsum[n] ----
// EXACT round-13/19/20 shape (112us/dispatch, no spill, VGPR=104). Do not touch.
__global__ __attribute__((amdgpu_flat_work_group_size(512, 512)))
__attribute__((amdgpu_waves_per_eu(2, 2)))
void fused_attn(
    const unsigned short* __restrict__ Q,    // xT [B][N][C] bf16
    const unsigned short* __restrict__ K,    // K'' [B][M][C] bf16 (b2 included)
    const unsigned short* __restrict__ Vt,   // [B][C][M] bf16 (bias included)
    const float* __restrict__ beta,          // [B][M]
    float* __restrict__ Z)                   // [B][N][C] +=
{
    extern __shared__ __align__(16) unsigned char smem[];
    // [K0 16K][K1 16K][V0 16K][V1 16K][V2 16K][P0 16K][P1 16K][rsl 1K][beta 4K]
    float* rsl = (float*)(smem + 114688);
    float* bs  = (float*)(smem + 115712);

    int z = blockIdx.z;
    int n0 = blockIdx.x * 128;
    int t = threadIdx.x, w = t >> 6, l = t & 63, g = l >> 4, c16 = l & 15;
    int wn = w >> 1, wc = w & 1;   // wave grid: 4 n-rows x 2 m/e-cols

    const unsigned short* Qb = Q + ((size_t)z * NN + n0) * CC;
    const char* Kzb = (const char*)(K + (size_t)z * MM * CC);
    const char* Vzb = (const char*)(Vt + (size_t)z * CC * MM);

    // beta table -> LDS (visible after prologue __syncthreads)
    bs[t] = beta[(size_t)z * MM + t];
    bs[t + 512] = beta[(size_t)z * MM + t + 512];

    // Q fragments: rows wn*32 + fi*16 + c16, k = ks*32 + g*8  (64 VGPR)
    s16x8 q[2][8];
#pragma unroll
    for (int fi = 0; fi < 2; ++fi)
#pragma unroll
        for (int ks = 0; ks < 8; ++ks)
            q[fi][ks] = *(const s16x8*)&Qb[(size_t)(wn * 32 + fi * 16 + c16) * CC + ks * 32 + g * 8];

    f32x4 o[2][8];
#pragma unroll
    for (int fi = 0; fi < 2; ++fi)
#pragma unroll
        for (int fj = 0; fj < 8; ++fj) o[fi][fj] = (f32x4){0.f, 0.f, 0.f, 0.f};
    float rs[2][4];
#pragma unroll
    for (int fi = 0; fi < 2; ++fi)
#pragma unroll
        for (int r = 0; r < 4; ++r) rs[fi][r] = 0.f;

    // gll staging (LDS linear, global source pre-XOR'd). K tile 16KB: 32 rows x 512B.
    auto issueK = [&](int buf, int m0) {
#pragma unroll
        for (int j = 0; j < 2; ++j) {
            int cid = w * 2 + j;
            int row = cid * 2 + (l >> 5);
            int srcoff = ((l & 31) * 16) ^ ((row & 7) << 4);
            const char* gp = Kzb + (size_t)(m0 + row) * 512 + srcoff;
            __builtin_amdgcn_global_load_lds(
                (const __attribute__((address_space(1))) void*)gp,
                (__attribute__((address_space(3))) void*)(smem + buf * 16384 + cid * 1024),
                16, 0, 0);
        }
    };
    // V tile 16KB: 256 rows x 64B; swizzle ^(((row>>1)&3)<<4) — bits 4-5 only (in-row)
    auto issueV = [&](int slot, int m0) {
#pragma unroll
        for (int j = 0; j < 2; ++j) {
            int cid = w * 2 + j;
            int row = cid * 16 + (l >> 2);
            int srcoff = ((l & 3) * 16) ^ (((row >> 1) & 3) << 4);
            const char* gp = Vzb + (size_t)row * 2048 + (size_t)m0 * 2 + srcoff;
            __builtin_amdgcn_global_load_lds(
                (const __attribute__((address_space(1))) void*)gp,
                (__attribute__((address_space(3))) void*)(smem + 32768 + slot * 16384 + cid * 1024),
                16, 0, 0);
        }
    };

    // QK(t)+exp -> P[par]. sacc: n-row = wn*32+fi*16+g*4+r, m = m0 + wc*16 + c16.
    auto qk_exp = [&](int buf, int par, int m0) {
        const unsigned char* Ks = smem + buf * 16384;
        unsigned char* Ps = smem + 81920 + par * 16384;
        f32x4 sacc[2];
#pragma unroll
        for (int fi = 0; fi < 2; ++fi) sacc[fi] = (f32x4){0.f, 0.f, 0.f, 0.f};
        int mr = wc * 16 + c16;
        __builtin_amdgcn_s_setprio(1);
#pragma unroll
        for (int ks = 0; ks < 8; ++ks) {
            s16x8 kf = *(const s16x8*)(Ks + ((mr * 512 + ks * 64 + g * 16) ^ ((mr & 7) << 4)));
#pragma unroll
            for (int fi = 0; fi < 2; ++fi)
                sacc[fi] = __builtin_amdgcn_mfma_f32_16x16x32_bf16(q[fi][ks], kf, sacc[fi], 0, 0, 0);
        }
        __builtin_amdgcn_s_setprio(0);
        float bet = bs[m0 + wc * 16 + c16];
#pragma unroll
        for (int fi = 0; fi < 2; ++fi)
#pragma unroll
            for (int r = 0; r < 4; ++r) {
                float e = __expf((sacc[fi][r] + bet) * SCALE);
                unsigned short h = f2bf(e);
                int nr = wn * 32 + fi * 16 + g * 4 + r;
                *(unsigned short*)(Ps + ((nr * 128 + (wc * 16 + c16) * 2) ^ ((nr & 7) << 4))) = h;
                rs[fi][r] += bf2f(h);
            }
    };
    // PV(t): O += P[par] · V[slot]
    auto pv = [&](int slot, int par) {
        const unsigned char* Vs = smem + 32768 + slot * 16384;
        const unsigned char* Ps = smem + 81920 + par * 16384;
        s16x8 pa[2];
#pragma unroll
        for (int fi = 0; fi < 2; ++fi) {
            int nr = wn * 32 + fi * 16 + c16;
            pa[fi] = *(const s16x8*)(Ps + ((nr * 128 + g * 16) ^ ((nr & 7) << 4)));
        }
        __builtin_amdgcn_s_setprio(1);
#pragma unroll
        for (int fj = 0; fj < 8; ++fj) {
            int er = wc * 128 + fj * 16 + c16;
            s16x8 vb = *(const s16x8*)(Vs + ((er * 64 + g * 16) ^ (((er >> 1) & 3) << 4)));
#pragma unroll
            for (int fi = 0; fi < 2; ++fi)
                o[fi][fj] = __builtin_amdgcn_mfma_f32_16x16x32_bf16(pa[fi], vb, o[fi][fj], 0, 0, 0);
        }
        __builtin_amdgcn_s_setprio(0);
    };

    // prologue: stage tiles 0,1; compute QK(0)->P[0]
    issueK(0, 0); issueV(0, 0);
    issueK(1, 32); issueV(1, 32);
    __syncthreads();
    qk_exp(0, 0, 0);

    for (int mt = 0; mt < 32; ++mt) {
        __syncthreads();   // publishes P[mt&1]; drains gll issued last interval
        if (mt < 30) {
            issueK(mt & 1, (mt + 2) * 32);
            issueV((mt + 2) % 3, (mt + 2) * 32);
        }
        __builtin_amdgcn_sched_barrier(0);
        if (mt < 31) qk_exp((mt + 1) & 1, (mt + 1) & 1, (mt + 1) * 32);
        pv(mt % 3, mt & 1);
    }

    // cross-lane + cross-wave rsum
#pragma unroll
    for (int fi = 0; fi < 2; ++fi)
#pragma unroll
        for (int r = 0; r < 4; ++r) {
            float v = rs[fi][r];
            v += __shfl_xor(v, 1); v += __shfl_xor(v, 2);
            v += __shfl_xor(v, 4); v += __shfl_xor(v, 8);
            if (c16 == 0) rsl[wc * 128 + wn * 32 + fi * 16 + g * 4 + r] = v;
        }
    __syncthreads();
    float* Zb = Z + ((size_t)z * NN + n0) * CC;
#pragma unroll
    for (int fi = 0; fi < 2; ++fi)
#pragma unroll
        for (int r = 0; r < 4; ++r) {
            int nr = wn * 32 + fi * 16 + g * 4 + r;
            float inv = 1.0f / (rsl[nr] + rsl[128 + nr]);
#pragma unroll
            for (int fj = 0; fj < 8; ++fj) {
                int e = wc * 128 + fj * 16 + c16;
                Zb[(size_t)nr * CC + e] += o[fi][fj][r] * inv;
            }
        }
}

// BN stats: per-channel sum and sumsq over B*N rows of Z [B*N][C]
__global__ __launch_bounds__(256) void bn_stats_kernel(const float* __restrict__ Z, float* __restrict__ bn) {
    int blk = blockIdx.x, e = threadIdx.x;
    const float* p = Z + (size_t)blk * 256 * CC + e;
    float s1 = 0.f, s2 = 0.f;
    for (int r = 0; r < 256; ++r) { float v = p[(size_t)r * CC]; s1 += v; s2 += v * v; }
    atomicAdd(&bn[e], s1);
    atomicAdd(&bn[CC + e], s2);
}

// normalize + relu + transpose [B][N][C] -> [B][C][N]
__global__ __launch_bounds__(256) void bn_apply_kernel(const float* __restrict__ Z, const float* __restrict__ bn,
                                                       const float* __restrict__ gamma, const float* __restrict__ beta,
                                                       float* __restrict__ out) {
    int b = blockIdx.z, e0 = blockIdx.y * 32, n0 = blockIdx.x * 32, t = threadIdx.x;
    __shared__ float tile[32][33];
    int c = t & 31, r0 = (t >> 5) * 4;
#pragma unroll
    for (int q = 0; q < 4; ++q)
        tile[r0 + q][c] = Z[((size_t)b * NN + n0 + r0 + q) * CC + e0 + c];
    __syncthreads();
    int n = t & 31, er0 = (t >> 5) * 4;
    const float invcnt = 1.0f / (BB * NN);
#pragma unroll
    for (int q = 0; q < 4; ++q) {
        int e = e0 + er0 + q;
        float mean = bn[e] * invcnt;
        float var = bn[CC + e] * invcnt - mean * mean;
        float rsq = rsqrtf(var + EPSV);
        float v = (tile[n][er0 + q] - mean) * rsq * gamma[e] + beta[e];
        out[((size_t)b * CC + e) * NN + n0 + n] = fmaxf(v, 0.f);
    }
}

extern "C" void kernel_launch(void* const* d_in, const int* in_sizes, int n_in,
                              void* d_out, int out_size, void* d_ws, size_t ws_size,
                              hipStream_t stream) {
    const float* x    = (const float*)d_in[0];
    const float* Wq_s = (const float*)d_in[2];  const float* bq_s = (const float*)d_in[3];
    const float* Wk_s = (const float*)d_in[4];  const float* bk_s = (const float*)d_in[5];
    const float* Wv_s = (const float*)d_in[6];  const float* bv_s = (const float*)d_in[7];
    const float* Wo_s = (const float*)d_in[8];  const float* bo_s = (const float*)d_in[9];
    const float* Wq_g = (const float*)d_in[10]; const float* bq_g = (const float*)d_in[11];
    const float* Wk_g = (const float*)d_in[12]; const float* bk_g = (const float*)d_in[13];
    const float* Wv_g = (const float*)d_in[14]; const float* bv_g = (const float*)d_in[15];
    const float* Wo_g = (const float*)d_in[16]; const float* bo_g = (const float*)d_in[17];
    const float* Wf   = (const float*)d_in[18]; const float* bf   = (const float*)d_in[19];
    const float* gamma = (const float*)d_in[20]; const float* beta = (const float*)d_in[21];

    float* ws    = (float*)d_ws;
    float* musum = ws + OFF_MU;
    float* score = ws + OFF_SCORE;
    int*   idx_s = (int*)(ws + OFF_IDX);
    int*   idx_g = idx_s + BB * MM;
    float* WoWv2 = ws + OFF_U;             // [2][65536]
    float* ubw   = ws + OFF_MU;            // per-branch u/b2/wob (musum dead after score_fix)
    float* beta2 = ws + OFF_SCORE;         // [2][B*M] (score dead after select)
    float* bvz2  = ws + OFF_BVZ;           // [2][256]
    unsigned short* Wvz2    = (unsigned short*)(ws + OFF_WVZ2);  // [2][65536]
    unsigned short* Wf12_16 = (unsigned short*)(ws + OFF_W16);
    unsigned short* W2pair  = Wf12_16 + 65536;                   // [2][65536]
    float* bz    = ws + OFF_W16 + 98304;   // last quarter of W16 region
    unsigned short* K2   = (unsigned short*)(ws + OFF_K16);      // [2][B*M*C]
    float* Z     = ws + OFF_Z;
    float* bn    = ws + OFF_BN;
    // d_out scratch: Xg2 [2][B*M*C] | Vt2 [2][B*C*M] | xT16 [B*N*C]  (all dead pre-bn_apply)
    unsigned short* Xg2  = (unsigned short*)d_out;
    unsigned short* Vt2  = Xg2 + (size_t)2 * BB * MM * CC;
    unsigned short* xT16 = (unsigned short*)d_out + (size_t)BB * NN * CC;

    zero_all_kernel<<<273, 256, 0, stream>>>(ws, bn);
    transpose_s2_kernel<<<dim3(NN / 32, CC / 32, BB), 256, 0, stream>>>(x, xT16, score, musum);
    score_fix_kernel<<<BB * NN / 4, 256, 0, stream>>>(xT16, musum, score);
    select_kernel<<<BB, 1024, 0, stream>>>(score, idx_s, idx_g);
    wf12bz_kernel<<<257, 256, 0, stream>>>(Wf, bf, bo_s, bo_g, Wf12_16, bz);
    // Z = xT @ Wf12^T + bz  (residual x through both conv halves)
    gemm_bt<0><<<dim3(512, 2, 1), 256, 0, stream>>>(xT16, 0, Wf12_16, 0, bz, 0, 0, Z, 0, CC);

    // both branches' precompute, batched over branch axis
    prep1_kernel<<<dim3(CC, 3, 2), 256, 0, stream>>>(
        Wo_s, Wv_s, Wq_s, Wk_s, bq_s, bk_s, bv_s,
        Wo_g, Wv_g, Wq_g, Wk_g, bq_g, bk_g, bv_g,
        WoWv2, W2pair, ubw);
    prep2_kernel<<<dim3(CC, 2), 256, 0, stream>>>(Wf, WoWv2, ubw, Wvz2, bvz2);
    gather_beta_kernel<<<dim3(BB * MM / 4, 2), 256, 0, stream>>>(xT16, idx_s, idx_g, ubw, Xg2, beta2);
    // K''[br] = Xg[br] @ W2[br]^T + b2[br]   (z = branch)
    gemm_bt<1><<<dim3(BB * MM / 128, 2, 2), 256, 0, stream>>>(
        Xg2, (size_t)BB * MM * CC, W2pair, 65536, ubw + 512, 2048, 0,
        K2, (size_t)BB * MM * CC, CC);
    // Vt[br][b] = Wvz[br] @ Xg[br][b]^T + bvz[br]   (z = br*16+batch; A/bias by z>>4)
    gemm_bt<2><<<dim3(2, 8, 2 * BB), 256, 0, stream>>>(
        Wvz2, 65536, Xg2, (size_t)MM * CC, bvz2, 256, 4,
        Vt2, (size_t)CC * MM, MM);

    // fused flash attention, one dispatch per branch (Z RMW must serialize)
    fused_attn<<<dim3(NN / 128, 1, BB), 512, 119808, stream>>>(
        xT16, K2, Vt2, beta2, Z);
    fused_attn<<<dim3(NN / 128, 1, BB), 512, 119808, stream>>>(
        xT16, K2 + (size_t)BB * MM * CC, Vt2 + (size_t)BB * CC * MM, beta2 + BB * MM, Z);

    bn_stats_kernel<<<BB * NN / 256, 256, 0, stream>>>(Z, bn);
    bn_apply_kernel<<<dim3(NN / 32, CC / 32, BB), 256, 0, stream>>>(Z, bn, gamma, beta, (float*)d_out);
}